// Round 2
// 1591.223 us; speedup vs baseline: 2.2256x; 2.2256x over previous
//
#include <hip/hip_runtime.h>
#include <math.h>

// Problem constants (B,L,E,H,D) = (8,1024,1024,16,64)
constexpr int Bc = 8;
constexpr int Lc = 1024;
constexpr int Ec = 1024;
constexpr int Hc = 16;
constexpr int Dc = 64;
constexpr float EPSc = 1e-5f;

// ---------------------------------------------------------------------------
// GEMM: C[M][N] = sum_k A[M][K] * B[N][K] + bias[N]   (both A and B K-contiguous)
// 128x128 tile, 256 threads, 8x8 micro-tile per thread, K-tile 16.
// ---------------------------------------------------------------------------
__global__ __launch_bounds__(256)
void gemm_nt(const float* __restrict__ A, const float* __restrict__ Bm,
             const float* __restrict__ bias, float* __restrict__ C,
             int M, int N, int K) {
    constexpr int TILE = 128;
    constexpr int KT = 16;
    __shared__ float As[KT][TILE];   // [k][m]
    __shared__ float Bs[KT][TILE];   // [k][n]

    const int tid = threadIdx.x;
    const int bm = blockIdx.x * TILE;
    const int bn = blockIdx.y * TILE;
    const int tx = tid & 15;         // n micro-tile index
    const int ty = tid >> 4;         // m micro-tile index

    float acc[8][8];
#pragma unroll
    for (int i = 0; i < 8; ++i)
#pragma unroll
        for (int j = 0; j < 8; ++j) acc[i][j] = 0.f;

    const int lr = tid >> 1;           // row within tile (0..127)
    const int lk = (tid & 1) * 8;      // k offset (0 or 8)
    const float* aptr = A + (size_t)(bm + lr) * K + lk;
    const float* bptr = Bm + (size_t)(bn + lr) * K + lk;

    for (int k0 = 0; k0 < K; k0 += KT) {
        float4 a0 = *(const float4*)(aptr + k0);
        float4 a1 = *(const float4*)(aptr + k0 + 4);
        float4 b0 = *(const float4*)(bptr + k0);
        float4 b1 = *(const float4*)(bptr + k0 + 4);
        __syncthreads();   // previous iteration's LDS reads complete
        As[lk + 0][lr] = a0.x; As[lk + 1][lr] = a0.y; As[lk + 2][lr] = a0.z; As[lk + 3][lr] = a0.w;
        As[lk + 4][lr] = a1.x; As[lk + 5][lr] = a1.y; As[lk + 6][lr] = a1.z; As[lk + 7][lr] = a1.w;
        Bs[lk + 0][lr] = b0.x; Bs[lk + 1][lr] = b0.y; Bs[lk + 2][lr] = b0.z; Bs[lk + 3][lr] = b0.w;
        Bs[lk + 4][lr] = b1.x; Bs[lk + 5][lr] = b1.y; Bs[lk + 6][lr] = b1.z; Bs[lk + 7][lr] = b1.w;
        __syncthreads();
#pragma unroll
        for (int k = 0; k < KT; ++k) {
            float4 av0 = *(const float4*)&As[k][ty * 8];
            float4 av1 = *(const float4*)&As[k][ty * 8 + 4];
            float4 bv0 = *(const float4*)&Bs[k][tx * 8];
            float4 bv1 = *(const float4*)&Bs[k][tx * 8 + 4];
            float av[8] = {av0.x, av0.y, av0.z, av0.w, av1.x, av1.y, av1.z, av1.w};
            float bv[8] = {bv0.x, bv0.y, bv0.z, bv0.w, bv1.x, bv1.y, bv1.z, bv1.w};
#pragma unroll
            for (int i = 0; i < 8; ++i)
#pragma unroll
                for (int j = 0; j < 8; ++j) acc[i][j] += av[i] * bv[j];
        }
    }

    const int col = bn + tx * 8;
    float4 bias0 = *(const float4*)(bias + col);
    float4 bias1 = *(const float4*)(bias + col + 4);
#pragma unroll
    for (int i = 0; i < 8; ++i) {
        size_t row = (size_t)(bm + ty * 8 + i);
        float4 c0 = {acc[i][0] + bias0.x, acc[i][1] + bias0.y, acc[i][2] + bias0.z, acc[i][3] + bias0.w};
        float4 c1 = {acc[i][4] + bias1.x, acc[i][5] + bias1.y, acc[i][6] + bias1.z, acc[i][7] + bias1.w};
        *(float4*)(C + row * N + col) = c0;
        *(float4*)(C + row * N + col + 4) = c1;
    }
}

// ---------------------------------------------------------------------------
// Attention v2: one block per (b, h, 128-query tile), 256 threads, 1 block/CU.
// No-max softmax (scores ~ N(0,1), exp safe in fp32):
//   Sweep 1: l_q = sum_k exp(s_qk), streamed, register-only.
//   Sweep 2: recompute s, w = exp(s)/l_q, w tile -> LDS [k][q], PV GEMM,
//            column sums of w -> avg_attn.
// QK^T micro-tile 8q x 8k per thread (4 x ds_read_b128 -> 64 FMA).
// PV micro-tile 8q x 8d per thread, k-split over 2 thread halves.
// ---------------------------------------------------------------------------
constexpr int QT = 128;       // queries per block
constexpr int KTILE = 128;    // keys per tile
constexpr int QPAD = 132;     // padded row for [d][q] / [k][q] tiles (mult of 4)
constexpr int VPAD = 68;      // padded row for [k][d] V tile

// smem layout (floats)
constexpr int Q_OFF  = 0;                    // Qs  [64][132]  = 8448
constexpr int KV_OFF = 8448;                 // K [64][132]=8448 or V [128][68]=8704
constexpr int W_OFF  = KV_OFF + 8704;        // wS  [128][132] = 16896
constexpr int COL_OFF = W_OFF + 16896;       // colAcc [1024]
constexpr int SMEM_FLOATS = COL_OFF + 1024;  // 35072 floats = 137 KiB

__global__ __launch_bounds__(256, 1)
void attn_kernel(const float* __restrict__ qkv, float* __restrict__ ctx,
                 float* __restrict__ avg_out) {
    __shared__ __align__(16) float smem[SMEM_FLOATS];
    float* Qs  = smem + Q_OFF;    // [d][q]: d*QPAD + q  (pre-scaled by 0.125)
    float* Kt  = smem + KV_OFF;   // [d][k]: d*QPAD + k
    float* Vt  = smem + KV_OFF;   // [k][d]: k*VPAD + d  (union with Kt)
    float* WS  = smem + W_OFF;    // [k][q]: k*QPAD + q
    float* COL = smem + COL_OFF;  // per-block column sums of w (1024)

    const int tid = threadIdx.x;
    const int qt = blockIdx.x;
    const int h  = blockIdx.y;
    const int b  = blockIdx.z;
    const int l0 = qt * QT;
    const size_t rowstride = 3 * Ec;
    const float* base = qkv + (size_t)b * Lc * rowstride + (size_t)h * Dc;

    const int sr = tid >> 1;           // staging row 0..127
    const int sh = (tid & 1) * 32;     // staging d-half offset

    // ---- stage Q transposed [d][q], scaled by 1/sqrt(D) ----
    {
        const float* src = base + (size_t)(l0 + sr) * rowstride + sh;
#pragma unroll
        for (int jj = 0; jj < 8; ++jj) {
            float4 v = *(const float4*)(src + jj * 4);
            int d0 = sh + jj * 4;
            Qs[(d0 + 0) * QPAD + sr] = v.x * 0.125f;
            Qs[(d0 + 1) * QPAD + sr] = v.y * 0.125f;
            Qs[(d0 + 2) * QPAD + sr] = v.z * 0.125f;
            Qs[(d0 + 3) * QPAD + sr] = v.w * 0.125f;
        }
    }

    const int ty = tid >> 4;   // q-block 0..15 (rows 8*ty .. 8*ty+7)
    const int tx = tid & 15;   // k-col group: cols {4tx..4tx+3} U {64+4tx..64+4tx+3}

    // ================= sweep 1: row sums of exp(scores) =================
    float rs[8];
#pragma unroll
    for (int i = 0; i < 8; ++i) rs[i] = 0.f;

    for (int kt = 0; kt < Lc / KTILE; ++kt) {
        __syncthreads();
        {   // stage K tile transposed [d][k]
            const float* src = base + (size_t)(kt * KTILE + sr) * rowstride + Ec + sh;
#pragma unroll
            for (int jj = 0; jj < 8; ++jj) {
                float4 v = *(const float4*)(src + jj * 4);
                int d0 = sh + jj * 4;
                Kt[(d0 + 0) * QPAD + sr] = v.x;
                Kt[(d0 + 1) * QPAD + sr] = v.y;
                Kt[(d0 + 2) * QPAD + sr] = v.z;
                Kt[(d0 + 3) * QPAD + sr] = v.w;
            }
        }
        __syncthreads();

        float acc[8][8];
#pragma unroll
        for (int i = 0; i < 8; ++i)
#pragma unroll
            for (int j = 0; j < 8; ++j) acc[i][j] = 0.f;

#pragma unroll 4
        for (int d = 0; d < Dc; ++d) {
            const float* qrow = Qs + d * QPAD;
            const float* krow = Kt + d * QPAD;
            float4 qa = *(const float4*)(qrow + ty * 8);
            float4 qb = *(const float4*)(qrow + ty * 8 + 4);
            float4 ka = *(const float4*)(krow + tx * 4);
            float4 kb = *(const float4*)(krow + 64 + tx * 4);
            float av[8] = {qa.x, qa.y, qa.z, qa.w, qb.x, qb.y, qb.z, qb.w};
            float bv[8] = {ka.x, ka.y, ka.z, ka.w, kb.x, kb.y, kb.z, kb.w};
#pragma unroll
            for (int i = 0; i < 8; ++i)
#pragma unroll
                for (int j = 0; j < 8; ++j) acc[i][j] += av[i] * bv[j];
        }
#pragma unroll
        for (int i = 0; i < 8; ++i) {
            float t = 0.f;
#pragma unroll
            for (int j = 0; j < 8; ++j) t += __expf(acc[i][j]);
            rs[i] += t;
        }
    }

    // reduce row sums across the 16 tx-threads (same ty) -> rinv per q-row
    float rinv[8];
#pragma unroll
    for (int i = 0; i < 8; ++i) {
        float v = rs[i];
        v += __shfl_xor(v, 1);
        v += __shfl_xor(v, 2);
        v += __shfl_xor(v, 4);
        v += __shfl_xor(v, 8);
        rinv[i] = 1.f / v;
    }

    // ================= sweep 2: recompute, normalize, PV, col sums =======
    const int qblk = (tid >> 3) & 15;  // PV q-block
    const int dblk = tid & 7;          // PV d-block
    const int kh   = tid >> 7;         // PV k-half

    float cacc[8][8];
#pragma unroll
    for (int i = 0; i < 8; ++i)
#pragma unroll
        for (int j = 0; j < 8; ++j) cacc[i][j] = 0.f;

    for (int kt = 0; kt < Lc / KTILE; ++kt) {
        __syncthreads();   // prior PV/colsum reads done
        {   // stage K tile transposed [d][k]
            const float* src = base + (size_t)(kt * KTILE + sr) * rowstride + Ec + sh;
#pragma unroll
            for (int jj = 0; jj < 8; ++jj) {
                float4 v = *(const float4*)(src + jj * 4);
                int d0 = sh + jj * 4;
                Kt[(d0 + 0) * QPAD + sr] = v.x;
                Kt[(d0 + 1) * QPAD + sr] = v.y;
                Kt[(d0 + 2) * QPAD + sr] = v.z;
                Kt[(d0 + 3) * QPAD + sr] = v.w;
            }
        }
        __syncthreads();

        float acc[8][8];
#pragma unroll
        for (int i = 0; i < 8; ++i)
#pragma unroll
            for (int j = 0; j < 8; ++j) acc[i][j] = 0.f;

#pragma unroll 4
        for (int d = 0; d < Dc; ++d) {
            const float* qrow = Qs + d * QPAD;
            const float* krow = Kt + d * QPAD;
            float4 qa = *(const float4*)(qrow + ty * 8);
            float4 qb = *(const float4*)(qrow + ty * 8 + 4);
            float4 ka = *(const float4*)(krow + tx * 4);
            float4 kb = *(const float4*)(krow + 64 + tx * 4);
            float av[8] = {qa.x, qa.y, qa.z, qa.w, qb.x, qb.y, qb.z, qb.w};
            float bv[8] = {ka.x, ka.y, ka.z, ka.w, kb.x, kb.y, kb.z, kb.w};
#pragma unroll
            for (int i = 0; i < 8; ++i)
#pragma unroll
                for (int j = 0; j < 8; ++j) acc[i][j] += av[i] * bv[j];
        }

        // normalize in-register: w = exp(s) * (1/l)
#pragma unroll
        for (int i = 0; i < 8; ++i)
#pragma unroll
            for (int j = 0; j < 8; ++j) acc[i][j] = __expf(acc[i][j]) * rinv[i];

        // transpose-write w -> WS[k][q]
#pragma unroll
        for (int j = 0; j < 8; ++j) {
            int col = (j < 4) ? (tx * 4 + j) : (60 + tx * 4 + j);  // 64 + 4tx + (j-4)
            float4 w0 = {acc[0][j], acc[1][j], acc[2][j], acc[3][j]};
            float4 w1 = {acc[4][j], acc[5][j], acc[6][j], acc[7][j]};
            *(float4*)&WS[col * QPAD + ty * 8]     = w0;
            *(float4*)&WS[col * QPAD + ty * 8 + 4] = w1;
        }
        __syncthreads();   // QK^T reads of Kt done; WS complete

        {   // stage V tile natural [k][d] (overwrites Kt region)
            const float* src = base + (size_t)(kt * KTILE + sr) * rowstride + 2 * Ec + sh;
#pragma unroll
            for (int jj = 0; jj < 8; ++jj) {
                float4 v = *(const float4*)(src + jj * 4);
                *(float4*)&Vt[sr * VPAD + sh + jj * 4] = v;
            }
        }
        __syncthreads();

        // PV: ctx[8q][8d] += w[8q][k] * V[k][8d], k over this thread's half
#pragma unroll 4
        for (int k = 0; k < 64; ++k) {
            int kk = kh * 64 + k;
            const float* wrow = WS + kk * QPAD + qblk * 8;
            const float* vrow = Vt + kk * VPAD + dblk * 8;
            float4 wa = *(const float4*)(wrow);
            float4 wb = *(const float4*)(wrow + 4);
            float4 va = *(const float4*)(vrow);
            float4 vb = *(const float4*)(vrow + 4);
            float wv[8] = {wa.x, wa.y, wa.z, wa.w, wb.x, wb.y, wb.z, wb.w};
            float vv[8] = {va.x, va.y, va.z, va.w, vb.x, vb.y, vb.z, vb.w};
#pragma unroll
            for (int i = 0; i < 8; ++i)
#pragma unroll
                for (int j = 0; j < 8; ++j) cacc[i][j] += wv[i] * vv[j];
        }

        // column sums of w (for avg_attn): row m of WS = w[*, key m]
        {
            int m = tid >> 1;
            int hh = (tid & 1) * 64;
            float s = 0.f;
#pragma unroll
            for (int t = 0; t < 16; ++t) {
                float4 v = *(const float4*)&WS[m * QPAD + hh + t * 4];
                s += v.x + v.y + v.z + v.w;
            }
            s += __shfl_xor(s, 1);
            if ((tid & 1) == 0) COL[kt * KTILE + m] = s;
        }
    }

    // ---- epilogue: combine k-halves, write ctx ----
    __syncthreads();
    float* red = WS;   // scratch: 128 slots x 64 floats
    if (kh == 1) {
        float* slot = red + (tid & 127) * 64;
#pragma unroll
        for (int i = 0; i < 8; ++i) {
            float4 c0 = {cacc[i][0], cacc[i][1], cacc[i][2], cacc[i][3]};
            float4 c1 = {cacc[i][4], cacc[i][5], cacc[i][6], cacc[i][7]};
            *(float4*)(slot + i * 8)     = c0;
            *(float4*)(slot + i * 8 + 4) = c1;
        }
    }
    __syncthreads();
    if (kh == 0) {
        float* slot = red + tid * 64;
#pragma unroll
        for (int i = 0; i < 8; ++i) {
            float4 o0 = *(const float4*)(slot + i * 8);
            float4 o1 = *(const float4*)(slot + i * 8 + 4);
            float4 c0 = {cacc[i][0] + o0.x, cacc[i][1] + o0.y, cacc[i][2] + o0.z, cacc[i][3] + o0.w};
            float4 c1 = {cacc[i][4] + o1.x, cacc[i][5] + o1.y, cacc[i][6] + o1.z, cacc[i][7] + o1.w};
            float* dst = ctx + (size_t)(b * Lc + l0 + qblk * 8 + i) * Ec + h * Dc + dblk * 8;
            *(float4*)(dst)     = c0;
            *(float4*)(dst + 4) = c1;
        }
    }

    // ---- flush avg_attn ----
    __syncthreads();
#pragma unroll
    for (int t = 0; t < 4; ++t) {
        int m = t * 256 + tid;
        atomicAdd(&avg_out[b * Lc + m], COL[m] * (1.0f / (Hc * Lc)));
    }
}

// ---------------------------------------------------------------------------
// LayerNorm stats: one block per (b,l) row. h = x + attn_out.
// ---------------------------------------------------------------------------
__global__ __launch_bounds__(256)
void stats_kernel(const float* __restrict__ x, const float* __restrict__ attn_out,
                  float2* __restrict__ stats) {
    const int row = blockIdx.x;
    const int tid = threadIdx.x;
    const float* xp = x + (size_t)row * Ec;
    const float* ap = attn_out + (size_t)row * Ec;
    float4 xv = *(const float4*)(xp + tid * 4);
    float4 av = *(const float4*)(ap + tid * 4);
    float h0 = xv.x + av.x, h1 = xv.y + av.y, h2 = xv.z + av.z, h3 = xv.w + av.w;
    float s = h0 + h1 + h2 + h3;
    float ss = h0 * h0 + h1 * h1 + h2 * h2 + h3 * h3;
#pragma unroll
    for (int off = 32; off; off >>= 1) {
        s += __shfl_xor(s, off);
        ss += __shfl_xor(ss, off);
    }
    __shared__ float wsum[4], wsq[4];
    const int wave = tid >> 6, lane = tid & 63;
    if (lane == 0) { wsum[wave] = s; wsq[wave] = ss; }
    __syncthreads();
    if (tid == 0) {
        float ts = wsum[0] + wsum[1] + wsum[2] + wsum[3];
        float tq = wsq[0] + wsq[1] + wsq[2] + wsq[3];
        float mean = ts * (1.0f / Ec);
        float var = tq * (1.0f / Ec) - mean * mean;
        stats[row] = make_float2(mean, rsqrtf(var + EPSc));
    }
}

// ---------------------------------------------------------------------------
// Pooled output: pooled[b][f] = mean_l( (h-mu)*rstd*gamma[f] + beta[f] )
// ---------------------------------------------------------------------------
__global__ __launch_bounds__(256)
void pool_kernel(const float* __restrict__ x, const float* __restrict__ attn_out,
                 const float2* __restrict__ stats, const float* __restrict__ gamma,
                 const float* __restrict__ beta, float* __restrict__ pooled) {
    const int b = blockIdx.z;
    const int f = blockIdx.y * 256 + threadIdx.x;
    const int l0 = blockIdx.x * 64;
    const float g = gamma[f];
    const float be = beta[f];
    float acc = 0.f;
    for (int l = l0; l < l0 + 64; ++l) {
        size_t idx = (size_t)(b * Lc + l) * Ec + f;
        float2 st = stats[b * Lc + l];
        float h = x[idx] + attn_out[idx];
        acc += (h - st.x) * st.y * g + be;
    }
    atomicAdd(&pooled[b * Ec + f], acc * (1.0f / Lc));
}

// ---------------------------------------------------------------------------
extern "C" void kernel_launch(void* const* d_in, const int* in_sizes, int n_in,
                              void* d_out, int out_size, void* d_ws, size_t ws_size,
                              hipStream_t stream) {
    const float* x      = (const float*)d_in[0];   // (B,L,E)
    const float* w_qkv  = (const float*)d_in[1];   // (3E,E)
    const float* b_qkv  = (const float*)d_in[2];   // (3E,)
    const float* w_out  = (const float*)d_in[3];   // (E,E)
    const float* b_out  = (const float*)d_in[4];   // (E,)
    const float* gamma  = (const float*)d_in[5];   // (E,)
    const float* beta   = (const float*)d_in[6];   // (E,)
    float* out = (float*)d_out;                    // pooled (B,E) then avg_attn (B,L)

    // workspace layout (floats): qkv 25165824 | ctx 8388608 | stats 16384
    float* qkv   = (float*)d_ws;
    float* ctx   = qkv + (size_t)Bc * Lc * 3 * Ec;
    float* stats = ctx + (size_t)Bc * Lc * Ec;
    float* attn_out = qkv;   // reuse: qkv dead after attention

    const int M = Bc * Lc;   // 8192

    hipMemsetAsync(d_out, 0, (size_t)out_size * sizeof(float), stream);

    // 1) QKV projection: (8192 x 1024) x (3072 x 1024)^T
    dim3 g1(M / 128, (3 * Ec) / 128);
    gemm_nt<<<g1, 256, 0, stream>>>(x, w_qkv, b_qkv, qkv, M, 3 * Ec, Ec);

    // 2) attention + avg_attn
    dim3 g2(Lc / QT, Hc, Bc);
    attn_kernel<<<g2, 256, 0, stream>>>(qkv, ctx, out + Bc * Ec);

    // 3) output projection: (8192 x 1024) x (1024 x 1024)^T  (writes over qkv)
    dim3 g3(M / 128, Ec / 128);
    gemm_nt<<<g3, 256, 0, stream>>>(ctx, w_out, b_out, attn_out, M, Ec, Ec);

    // 4) LN stats
    stats_kernel<<<M, 256, 0, stream>>>(x, attn_out, (float2*)stats);

    // 5) pooled
    dim3 g5(16, 4, Bc);
    pool_kernel<<<g5, 256, 0, stream>>>(x, attn_out, (float2*)stats, gamma, beta, out);
}

// Round 3
// 1377.901 us; speedup vs baseline: 2.5702x; 1.1548x over previous
//
#include <hip/hip_runtime.h>
#include <math.h>

// Problem constants (B,L,E,H,D) = (8,1024,1024,16,64)
constexpr int Bc = 8;
constexpr int Lc = 1024;
constexpr int Ec = 1024;
constexpr int Hc = 16;
constexpr int Dc = 64;
constexpr float EPSc = 1e-5f;

// ---- fp16 pair type for v_dot2_f32_f16 ----
typedef _Float16 f16;
typedef f16 f16x2 __attribute__((ext_vector_type(2)));
struct alignas(16) H2x4 { f16x2 v[4]; };

#if defined(__has_builtin)
#if __has_builtin(__builtin_amdgcn_fdot2)
#define HAVE_FDOT2 1
#endif
#endif
#ifdef HAVE_FDOT2
#define FDOT2(a, b, c) __builtin_amdgcn_fdot2((a), (b), (c), false)
#else
#define FDOT2(a, b, c) ((c) + (float)(a)[0] * (float)(b)[0] + (float)(a)[1] * (float)(b)[1])
#endif

static __device__ inline f16x2 pack2(float x, float y) {
    f16x2 r;
    r[0] = (f16)x;
    r[1] = (f16)y;
    return r;
}

// ---------------------------------------------------------------------------
// GEMM: C[M][N] = sum_k A[M][K] * B[N][K] + bias[N]   (both A and B K-contiguous)
// 128x128 tile, 256 threads, 8x8 micro-tile per thread, K-tile 16.  (UNCHANGED)
// ---------------------------------------------------------------------------
__global__ __launch_bounds__(256)
void gemm_nt(const float* __restrict__ A, const float* __restrict__ Bm,
             const float* __restrict__ bias, float* __restrict__ C,
             int M, int N, int K) {
    constexpr int TILE = 128;
    constexpr int KT = 16;
    __shared__ float As[KT][TILE];   // [k][m]
    __shared__ float Bs[KT][TILE];   // [k][n]

    const int tid = threadIdx.x;
    const int bm = blockIdx.x * TILE;
    const int bn = blockIdx.y * TILE;
    const int tx = tid & 15;         // n micro-tile index
    const int ty = tid >> 4;         // m micro-tile index

    float acc[8][8];
#pragma unroll
    for (int i = 0; i < 8; ++i)
#pragma unroll
        for (int j = 0; j < 8; ++j) acc[i][j] = 0.f;

    const int lr = tid >> 1;           // row within tile (0..127)
    const int lk = (tid & 1) * 8;      // k offset (0 or 8)
    const float* aptr = A + (size_t)(bm + lr) * K + lk;
    const float* bptr = Bm + (size_t)(bn + lr) * K + lk;

    for (int k0 = 0; k0 < K; k0 += KT) {
        float4 a0 = *(const float4*)(aptr + k0);
        float4 a1 = *(const float4*)(aptr + k0 + 4);
        float4 b0 = *(const float4*)(bptr + k0);
        float4 b1 = *(const float4*)(bptr + k0 + 4);
        __syncthreads();   // previous iteration's LDS reads complete
        As[lk + 0][lr] = a0.x; As[lk + 1][lr] = a0.y; As[lk + 2][lr] = a0.z; As[lk + 3][lr] = a0.w;
        As[lk + 4][lr] = a1.x; As[lk + 5][lr] = a1.y; As[lk + 6][lr] = a1.z; As[lk + 7][lr] = a1.w;
        Bs[lk + 0][lr] = b0.x; Bs[lk + 1][lr] = b0.y; Bs[lk + 2][lr] = b0.z; Bs[lk + 3][lr] = b0.w;
        Bs[lk + 4][lr] = b1.x; Bs[lk + 5][lr] = b1.y; Bs[lk + 6][lr] = b1.z; Bs[lk + 7][lr] = b1.w;
        __syncthreads();
#pragma unroll
        for (int k = 0; k < KT; ++k) {
            float4 av0 = *(const float4*)&As[k][ty * 8];
            float4 av1 = *(const float4*)&As[k][ty * 8 + 4];
            float4 bv0 = *(const float4*)&Bs[k][tx * 8];
            float4 bv1 = *(const float4*)&Bs[k][tx * 8 + 4];
            float av[8] = {av0.x, av0.y, av0.z, av0.w, av1.x, av1.y, av1.z, av1.w};
            float bv[8] = {bv0.x, bv0.y, bv0.z, bv0.w, bv1.x, bv1.y, bv1.z, bv1.w};
#pragma unroll
            for (int i = 0; i < 8; ++i)
#pragma unroll
                for (int j = 0; j < 8; ++j) acc[i][j] += av[i] * bv[j];
        }
    }

    const int col = bn + tx * 8;
    float4 bias0 = *(const float4*)(bias + col);
    float4 bias1 = *(const float4*)(bias + col + 4);
#pragma unroll
    for (int i = 0; i < 8; ++i) {
        size_t row = (size_t)(bm + ty * 8 + i);
        float4 c0 = {acc[i][0] + bias0.x, acc[i][1] + bias0.y, acc[i][2] + bias0.z, acc[i][3] + bias0.w};
        float4 c1 = {acc[i][4] + bias1.x, acc[i][5] + bias1.y, acc[i][6] + bias1.z, acc[i][7] + bias1.w};
        *(float4*)(C + row * N + col) = c0;
        *(float4*)(C + row * N + col + 4) = c1;
    }
}

// ---------------------------------------------------------------------------
// Attention v3: fp16-pair LDS tiles + v_dot2_f32_f16, fp32 accumulation.
// One block per (b, h, 128-query tile), 256 threads; LDS 70.5 KB -> 2 blocks/CU.
// No-max softmax (scores ~ N(0,1)):
//   Sweep 1: l_q = sum_k exp(s_qk) (register-only).
//   Sweep 2: recompute s, w = exp(s)*rinv -> fp16 WS2 [kpair][q];
//            PV via dot2 over k-pairs; column sums of w -> avg_attn.
// Layouts (f16x2 units, 4B): Qs2/Kt2 [32 dpair][132], Vt2 [64 kpair][68],
//   WS2 [64 kpair][132], COL fp32[1024].
// ---------------------------------------------------------------------------
constexpr int QT = 128;       // queries per block
constexpr int KTILE = 128;    // keys per tile
constexpr int QP2 = 132;      // row stride (f16x2 units) for Qs2/Kt2/WS2
constexpr int VP2 = 68;       // row stride (f16x2 units) for Vt2

// smem offsets in 4-byte words
constexpr int Q_OFF  = 0;                    // Qs2  32*132 = 4224
constexpr int KV_OFF = 4224;                 // Kt2 32*132=4224 | Vt2 64*68=4352
constexpr int W_OFF  = KV_OFF + 4352;        // WS2 64*132 = 8448
constexpr int COL_OFF = W_OFF + 8448;        // COL fp32 [1024]
constexpr int SMEM_WORDS = COL_OFF + 1024;   // 18048 words = 72192 B

__global__ __launch_bounds__(256, 2)
void attn_kernel(const float* __restrict__ qkv, float* __restrict__ ctx,
                 float* __restrict__ avg_out) {
    __shared__ __align__(16) float smemf[SMEM_WORDS];
    f16x2* Qs2 = (f16x2*)(smemf + Q_OFF);   // [dp][q]: {Q[q][2dp],Q[q][2dp+1]} * 0.125
    f16x2* Kt2 = (f16x2*)(smemf + KV_OFF);  // [dp][k]: {K[k][2dp],K[k][2dp+1]}
    f16x2* Vt2 = (f16x2*)(smemf + KV_OFF);  // [kp][d]: {V[2kp][d],V[2kp+1][d]} (union)
    f16x2* WS2 = (f16x2*)(smemf + W_OFF);   // [kp][q]: {w[q][2kp],w[q][2kp+1]}
    float* COL = smemf + COL_OFF;           // col sums of w (this block's 128 q)

    const int tid = threadIdx.x;
    const int qt = blockIdx.x;
    const int h  = blockIdx.y;
    const int b  = blockIdx.z;
    const int l0 = qt * QT;
    const size_t rowstride = 3 * Ec;
    const float* base = qkv + (size_t)b * Lc * rowstride + (size_t)h * Dc;

    const int sr = tid >> 1;           // staging row 0..127
    const int sh = (tid & 1) * 32;     // staging d-half offset

    // ---- stage Q as d-pairs [dp][q], scaled by 1/sqrt(D) ----
    {
        const float* src = base + (size_t)(l0 + sr) * rowstride + sh;
#pragma unroll
        for (int jj = 0; jj < 8; ++jj) {
            float4 v = *(const float4*)(src + jj * 4);
            int dp = (sh >> 1) + jj * 2;
            Qs2[(dp + 0) * QP2 + sr] = pack2(v.x * 0.125f, v.y * 0.125f);
            Qs2[(dp + 1) * QP2 + sr] = pack2(v.z * 0.125f, v.w * 0.125f);
        }
    }

    const int ty = tid >> 4;   // q-block 0..15 (rows 8*ty .. 8*ty+7)
    const int tx = tid & 15;   // k cols {4tx..4tx+3} U {64+4tx..64+4tx+3}

    // ================= sweep 1: row sums of exp(scores) =================
    float rs[8];
#pragma unroll
    for (int i = 0; i < 8; ++i) rs[i] = 0.f;

    for (int kt = 0; kt < Lc / KTILE; ++kt) {
        __syncthreads();
        {   // stage K tile as d-pairs [dp][k]
            const float* src = base + (size_t)(kt * KTILE + sr) * rowstride + Ec + sh;
#pragma unroll
            for (int jj = 0; jj < 8; ++jj) {
                float4 v = *(const float4*)(src + jj * 4);
                int dp = (sh >> 1) + jj * 2;
                Kt2[(dp + 0) * QP2 + sr] = pack2(v.x, v.y);
                Kt2[(dp + 1) * QP2 + sr] = pack2(v.z, v.w);
            }
        }
        __syncthreads();

        float acc[8][8];
#pragma unroll
        for (int i = 0; i < 8; ++i)
#pragma unroll
            for (int j = 0; j < 8; ++j) acc[i][j] = 0.f;

#pragma unroll 4
        for (int dp = 0; dp < Dc / 2; ++dp) {
            const f16x2* qrow = Qs2 + dp * QP2;
            const f16x2* krow = Kt2 + dp * QP2;
            H2x4 qa = *(const H2x4*)(qrow + ty * 8);
            H2x4 qb = *(const H2x4*)(qrow + ty * 8 + 4);
            H2x4 ka = *(const H2x4*)(krow + tx * 4);
            H2x4 kb = *(const H2x4*)(krow + 64 + tx * 4);
#pragma unroll
            for (int i = 0; i < 8; ++i) {
                f16x2 q2 = (i < 4) ? qa.v[i] : qb.v[i - 4];
#pragma unroll
                for (int j = 0; j < 8; ++j) {
                    f16x2 k2 = (j < 4) ? ka.v[j] : kb.v[j - 4];
                    acc[i][j] = FDOT2(q2, k2, acc[i][j]);
                }
            }
        }
#pragma unroll
        for (int i = 0; i < 8; ++i) {
            float t = 0.f;
#pragma unroll
            for (int j = 0; j < 8; ++j) t += __expf(acc[i][j]);
            rs[i] += t;
        }
    }

    // reduce row sums across the 16 tx-threads (same ty) -> rinv per q-row
    float rinv[8];
#pragma unroll
    for (int i = 0; i < 8; ++i) {
        float v = rs[i];
        v += __shfl_xor(v, 1);
        v += __shfl_xor(v, 2);
        v += __shfl_xor(v, 4);
        v += __shfl_xor(v, 8);
        rinv[i] = 1.f / v;
    }

    // ================= sweep 2: recompute, normalize, PV, col sums =======
    const int qblk = (tid >> 3) & 15;  // PV q-block
    const int dblk = tid & 7;          // PV d-block
    const int kh   = tid >> 7;         // PV k-half (32 k-pairs each)

    float cacc[8][8];
#pragma unroll
    for (int i = 0; i < 8; ++i)
#pragma unroll
        for (int j = 0; j < 8; ++j) cacc[i][j] = 0.f;

    for (int kt = 0; kt < Lc / KTILE; ++kt) {
        __syncthreads();   // prior PV/colsum reads of Vt2/WS2 done
        {   // stage K tile as d-pairs [dp][k]
            const float* src = base + (size_t)(kt * KTILE + sr) * rowstride + Ec + sh;
#pragma unroll
            for (int jj = 0; jj < 8; ++jj) {
                float4 v = *(const float4*)(src + jj * 4);
                int dp = (sh >> 1) + jj * 2;
                Kt2[(dp + 0) * QP2 + sr] = pack2(v.x, v.y);
                Kt2[(dp + 1) * QP2 + sr] = pack2(v.z, v.w);
            }
        }
        __syncthreads();

        float acc[8][8];
#pragma unroll
        for (int i = 0; i < 8; ++i)
#pragma unroll
            for (int j = 0; j < 8; ++j) acc[i][j] = 0.f;

#pragma unroll 4
        for (int dp = 0; dp < Dc / 2; ++dp) {
            const f16x2* qrow = Qs2 + dp * QP2;
            const f16x2* krow = Kt2 + dp * QP2;
            H2x4 qa = *(const H2x4*)(qrow + ty * 8);
            H2x4 qb = *(const H2x4*)(qrow + ty * 8 + 4);
            H2x4 ka = *(const H2x4*)(krow + tx * 4);
            H2x4 kb = *(const H2x4*)(krow + 64 + tx * 4);
#pragma unroll
            for (int i = 0; i < 8; ++i) {
                f16x2 q2 = (i < 4) ? qa.v[i] : qb.v[i - 4];
#pragma unroll
                for (int j = 0; j < 8; ++j) {
                    f16x2 k2 = (j < 4) ? ka.v[j] : kb.v[j - 4];
                    acc[i][j] = FDOT2(q2, k2, acc[i][j]);
                }
            }
        }

        // normalize in-register: w = exp(s) * (1/l)
#pragma unroll
        for (int i = 0; i < 8; ++i)
#pragma unroll
            for (int j = 0; j < 8; ++j) acc[i][j] = __expf(acc[i][j]) * rinv[i];

        // pack w into k-pair fp16 and write WS2[kp][q]
#pragma unroll
        for (int j = 0; j < 2; ++j) {
            {   // low cols: k = 4tx+2j, 4tx+2j+1  -> kp = 2tx+j
                f16x2* dst = WS2 + (2 * tx + j) * QP2 + ty * 8;
#pragma unroll
                for (int i = 0; i < 8; ++i) dst[i] = pack2(acc[i][2 * j], acc[i][2 * j + 1]);
            }
            {   // high cols: k = 64+4tx+2j, +1 -> kp = 32+2tx+j
                f16x2* dst = WS2 + (32 + 2 * tx + j) * QP2 + ty * 8;
#pragma unroll
                for (int i = 0; i < 8; ++i) dst[i] = pack2(acc[i][4 + 2 * j], acc[i][5 + 2 * j]);
            }
        }
        __syncthreads();   // Kt2 reads done by all; WS2 writes visible

        {   // stage V tile k-pair interleaved: Vt2[kp][d] = {V[2kp][d], V[2kp+1][d]}
            int kp = tid >> 2;
            int dq = (tid & 3) * 16;
            const float* s0 = base + (size_t)(kt * KTILE + 2 * kp) * rowstride + 2 * Ec + dq;
            const float* s1 = s0 + rowstride;
            f16x2* dst = Vt2 + kp * VP2 + dq;
#pragma unroll
            for (int jj = 0; jj < 4; ++jj) {
                float4 a = *(const float4*)(s0 + jj * 4);
                float4 bb = *(const float4*)(s1 + jj * 4);
                dst[jj * 4 + 0] = pack2(a.x, bb.x);
                dst[jj * 4 + 1] = pack2(a.y, bb.y);
                dst[jj * 4 + 2] = pack2(a.z, bb.z);
                dst[jj * 4 + 3] = pack2(a.w, bb.w);
            }
        }
        __syncthreads();

        // PV: ctx[8q][8d] += w2[q][kp] . v2[kp][d] over this thread's 32 k-pairs
#pragma unroll 4
        for (int kp = 0; kp < 32; ++kp) {
            int kk = kh * 32 + kp;
            const f16x2* wrow = WS2 + kk * QP2 + qblk * 8;
            const f16x2* vrow = Vt2 + kk * VP2 + dblk * 8;
            H2x4 wa = *(const H2x4*)(wrow);
            H2x4 wb = *(const H2x4*)(wrow + 4);
            H2x4 va = *(const H2x4*)(vrow);
            H2x4 vb = *(const H2x4*)(vrow + 4);
#pragma unroll
            for (int i = 0; i < 8; ++i) {
                f16x2 w2 = (i < 4) ? wa.v[i] : wb.v[i - 4];
#pragma unroll
                for (int j = 0; j < 8; ++j) {
                    f16x2 v2 = (j < 4) ? va.v[j] : vb.v[j - 4];
                    cacc[i][j] = FDOT2(w2, v2, cacc[i][j]);
                }
            }
        }

        // column sums of w (for avg_attn): row kp of WS2 = keys 2kp, 2kp+1
        {
            int kpc = tid >> 2;        // 0..63
            int qq = tid & 3;          // quarter of q-range
            const f16x2* wr = WS2 + kpc * QP2 + qq * 32;
            float sx = 0.f, sy = 0.f;
#pragma unroll
            for (int t = 0; t < 8; ++t) {
                H2x4 w = *(const H2x4*)(wr + t * 4);
#pragma unroll
                for (int c = 0; c < 4; ++c) {
                    sx += (float)w.v[c][0];
                    sy += (float)w.v[c][1];
                }
            }
            sx += __shfl_xor(sx, 1); sx += __shfl_xor(sx, 2);
            sy += __shfl_xor(sy, 1); sy += __shfl_xor(sy, 2);
            if (qq == 0) {
                COL[kt * KTILE + 2 * kpc]     = sx;
                COL[kt * KTILE + 2 * kpc + 1] = sy;
            }
        }
    }

    // ---- epilogue: combine k-halves, write ctx ----
    __syncthreads();
    float* red = smemf + W_OFF;   // scratch: 128 slots x 64 floats (8192 <= 8448)
    if (kh == 1) {
        float* slot = red + (tid & 127) * 64;
#pragma unroll
        for (int i = 0; i < 8; ++i) {
            float4 c0 = {cacc[i][0], cacc[i][1], cacc[i][2], cacc[i][3]};
            float4 c1 = {cacc[i][4], cacc[i][5], cacc[i][6], cacc[i][7]};
            *(float4*)(slot + i * 8)     = c0;
            *(float4*)(slot + i * 8 + 4) = c1;
        }
    }
    __syncthreads();
    if (kh == 0) {
        float* slot = red + tid * 64;
#pragma unroll
        for (int i = 0; i < 8; ++i) {
            float4 o0 = *(const float4*)(slot + i * 8);
            float4 o1 = *(const float4*)(slot + i * 8 + 4);
            float4 c0 = {cacc[i][0] + o0.x, cacc[i][1] + o0.y, cacc[i][2] + o0.z, cacc[i][3] + o0.w};
            float4 c1 = {cacc[i][4] + o1.x, cacc[i][5] + o1.y, cacc[i][6] + o1.z, cacc[i][7] + o1.w};
            float* dst = ctx + (size_t)(b * Lc + l0 + qblk * 8 + i) * Ec + h * Dc + dblk * 8;
            *(float4*)(dst)     = c0;
            *(float4*)(dst + 4) = c1;
        }
    }

    // ---- flush avg_attn ----
    __syncthreads();
#pragma unroll
    for (int t = 0; t < 4; ++t) {
        int m = t * 256 + tid;
        atomicAdd(&avg_out[b * Lc + m], COL[m] * (1.0f / (Hc * Lc)));
    }
}

// ---------------------------------------------------------------------------
// LayerNorm stats: one block per (b,l) row. h = x + attn_out.  (UNCHANGED)
// ---------------------------------------------------------------------------
__global__ __launch_bounds__(256)
void stats_kernel(const float* __restrict__ x, const float* __restrict__ attn_out,
                  float2* __restrict__ stats) {
    const int row = blockIdx.x;
    const int tid = threadIdx.x;
    const float* xp = x + (size_t)row * Ec;
    const float* ap = attn_out + (size_t)row * Ec;
    float4 xv = *(const float4*)(xp + tid * 4);
    float4 av = *(const float4*)(ap + tid * 4);
    float h0 = xv.x + av.x, h1 = xv.y + av.y, h2 = xv.z + av.z, h3 = xv.w + av.w;
    float s = h0 + h1 + h2 + h3;
    float ss = h0 * h0 + h1 * h1 + h2 * h2 + h3 * h3;
#pragma unroll
    for (int off = 32; off; off >>= 1) {
        s += __shfl_xor(s, off);
        ss += __shfl_xor(ss, off);
    }
    __shared__ float wsum[4], wsq[4];
    const int wave = tid >> 6, lane = tid & 63;
    if (lane == 0) { wsum[wave] = s; wsq[wave] = ss; }
    __syncthreads();
    if (tid == 0) {
        float ts = wsum[0] + wsum[1] + wsum[2] + wsum[3];
        float tq = wsq[0] + wsq[1] + wsq[2] + wsq[3];
        float mean = ts * (1.0f / Ec);
        float var = tq * (1.0f / Ec) - mean * mean;
        stats[row] = make_float2(mean, rsqrtf(var + EPSc));
    }
}

// ---------------------------------------------------------------------------
// Pooled output: pooled[b][f] = mean_l( (h-mu)*rstd*gamma[f] + beta[f] )  (UNCHANGED)
// ---------------------------------------------------------------------------
__global__ __launch_bounds__(256)
void pool_kernel(const float* __restrict__ x, const float* __restrict__ attn_out,
                 const float2* __restrict__ stats, const float* __restrict__ gamma,
                 const float* __restrict__ beta, float* __restrict__ pooled) {
    const int b = blockIdx.z;
    const int f = blockIdx.y * 256 + threadIdx.x;
    const int l0 = blockIdx.x * 64;
    const float g = gamma[f];
    const float be = beta[f];
    float acc = 0.f;
    for (int l = l0; l < l0 + 64; ++l) {
        size_t idx = (size_t)(b * Lc + l) * Ec + f;
        float2 st = stats[b * Lc + l];
        float h = x[idx] + attn_out[idx];
        acc += (h - st.x) * st.y * g + be;
    }
    atomicAdd(&pooled[b * Ec + f], acc * (1.0f / Lc));
}

// ---------------------------------------------------------------------------
extern "C" void kernel_launch(void* const* d_in, const int* in_sizes, int n_in,
                              void* d_out, int out_size, void* d_ws, size_t ws_size,
                              hipStream_t stream) {
    const float* x      = (const float*)d_in[0];   // (B,L,E)
    const float* w_qkv  = (const float*)d_in[1];   // (3E,E)
    const float* b_qkv  = (const float*)d_in[2];   // (3E,)
    const float* w_out  = (const float*)d_in[3];   // (E,E)
    const float* b_out  = (const float*)d_in[4];   // (E,)
    const float* gamma  = (const float*)d_in[5];   // (E,)
    const float* beta   = (const float*)d_in[6];   // (E,)
    float* out = (float*)d_out;                    // pooled (B,E) then avg_attn (B,L)

    // workspace layout (floats): qkv 25165824 | ctx 8388608 | stats 16384
    float* qkv   = (float*)d_ws;
    float* ctx   = qkv + (size_t)Bc * Lc * 3 * Ec;
    float* stats = ctx + (size_t)Bc * Lc * Ec;
    float* attn_out = qkv;   // reuse: qkv dead after attention

    const int M = Bc * Lc;   // 8192

    hipMemsetAsync(d_out, 0, (size_t)out_size * sizeof(float), stream);

    // 1) QKV projection: (8192 x 1024) x (3072 x 1024)^T
    dim3 g1(M / 128, (3 * Ec) / 128);
    gemm_nt<<<g1, 256, 0, stream>>>(x, w_qkv, b_qkv, qkv, M, 3 * Ec, Ec);

    // 2) attention + avg_attn
    dim3 g2(Lc / QT, Hc, Bc);
    attn_kernel<<<g2, 256, 0, stream>>>(qkv, ctx, out + Bc * Ec);

    // 3) output projection: (8192 x 1024) x (1024 x 1024)^T  (writes over qkv)
    dim3 g3(M / 128, Ec / 128);
    gemm_nt<<<g3, 256, 0, stream>>>(ctx, w_out, b_out, attn_out, M, Ec, Ec);

    // 4) LN stats
    stats_kernel<<<M, 256, 0, stream>>>(x, attn_out, (float2*)stats);

    // 5) pooled
    dim3 g5(16, 4, Bc);
    pool_kernel<<<g5, 256, 0, stream>>>(x, attn_out, (float2*)stats, gamma, beta, out);
}

// Round 4
// 745.825 us; speedup vs baseline: 4.7484x; 1.8475x over previous
//
#include <hip/hip_runtime.h>
#include <math.h>

// Problem constants (B,L,E,H,D) = (8,1024,1024,16,64)
constexpr int Bc = 8;
constexpr int Lc = 1024;
constexpr int Ec = 1024;
constexpr int Hc = 16;
constexpr int Dc = 64;
constexpr float EPSc = 1e-5f;

// ---- fp16 types ----
typedef _Float16 f16;
typedef f16 f16x2 __attribute__((ext_vector_type(2)));
typedef f16 half8 __attribute__((ext_vector_type(8)));
typedef float floatx4 __attribute__((ext_vector_type(4)));
struct alignas(16) H2x4 { f16x2 v[4]; };

#if defined(__has_builtin)
#if __has_builtin(__builtin_amdgcn_fdot2)
#define HAVE_FDOT2 1
#endif
#endif
#ifdef HAVE_FDOT2
#define FDOT2(a, b, c) __builtin_amdgcn_fdot2((a), (b), (c), false)
#else
#define FDOT2(a, b, c) ((c) + (float)(a)[0] * (float)(b)[0] + (float)(a)[1] * (float)(b)[1])
#endif

static __device__ inline f16x2 pack2(float x, float y) {
    f16x2 r;
    r[0] = (f16)x;
    r[1] = (f16)y;
    return r;
}

// ---------------------------------------------------------------------------
// GEMM v2 (MFMA fp16): C[M][N] = sum_k A[M][K]*B[N][K] + bias[N], fp32 accum.
// 128x128 tile, 256 threads = 4 waves in 2x2; each wave owns a 64x64 sub-tile
// (4x4 MFMA 16x16 tiles). KT=32 = one v_mfma_f32_16x16x32_f16 per tile per step.
// LDS: A/B tiles as fp16 [row][k], row padded to 40 f16 (80 B) -> <=2-way banks.
// Fragment maps (guide §3, m89): A/B lane l -> row/col l&15, k = 8*(l>>4)..+7;
// C/D lane l -> col l&15, row (l>>4)*4 + reg.
// ---------------------------------------------------------------------------
__global__ __launch_bounds__(256)
void gemm_nt(const float* __restrict__ A, const float* __restrict__ Bm,
             const float* __restrict__ bias, float* __restrict__ C,
             int M, int N, int K) {
    constexpr int TILE = 128;
    constexpr int KT = 32;
    constexpr int KP = 40;                 // padded row length in f16
    __shared__ f16 As[TILE * KP];          // 10240 B
    __shared__ f16 Bs[TILE * KP];          // 10240 B

    const int tid = threadIdx.x;
    const int bm = blockIdx.x * TILE;
    const int bn = blockIdx.y * TILE;

    const int wave = tid >> 6;
    const int lane = tid & 63;
    const int wm = (wave >> 1) * 64;       // wave sub-tile origin (m)
    const int wn = (wave & 1) * 64;        // wave sub-tile origin (n)
    const int r16 = lane & 15;
    const int kg = lane >> 4;              // k-group 0..3 (k = 8*kg..8*kg+7)

    floatx4 acc[4][4];
#pragma unroll
    for (int i = 0; i < 4; ++i)
#pragma unroll
        for (int j = 0; j < 4; ++j) acc[i][j] = (floatx4){0.f, 0.f, 0.f, 0.f};

    // staging: thread -> row tid>>1 (0..127), k-half (tid&1)*16
    const int srow = tid >> 1;
    const int skh = (tid & 1) * 16;
    const float* aptr = A + (size_t)(bm + srow) * K + skh;
    const float* bptr = Bm + (size_t)(bn + srow) * K + skh;

    for (int k0 = 0; k0 < K; k0 += KT) {
        float4 a0 = *(const float4*)(aptr + k0);
        float4 a1 = *(const float4*)(aptr + k0 + 4);
        float4 a2 = *(const float4*)(aptr + k0 + 8);
        float4 a3 = *(const float4*)(aptr + k0 + 12);
        float4 b0 = *(const float4*)(bptr + k0);
        float4 b1 = *(const float4*)(bptr + k0 + 4);
        float4 b2 = *(const float4*)(bptr + k0 + 8);
        float4 b3 = *(const float4*)(bptr + k0 + 12);
        __syncthreads();   // previous iteration's LDS reads complete
        {
            half8 pa0, pa1, pb0, pb1;
            pa0[0] = (f16)a0.x; pa0[1] = (f16)a0.y; pa0[2] = (f16)a0.z; pa0[3] = (f16)a0.w;
            pa0[4] = (f16)a1.x; pa0[5] = (f16)a1.y; pa0[6] = (f16)a1.z; pa0[7] = (f16)a1.w;
            pa1[0] = (f16)a2.x; pa1[1] = (f16)a2.y; pa1[2] = (f16)a2.z; pa1[3] = (f16)a2.w;
            pa1[4] = (f16)a3.x; pa1[5] = (f16)a3.y; pa1[6] = (f16)a3.z; pa1[7] = (f16)a3.w;
            pb0[0] = (f16)b0.x; pb0[1] = (f16)b0.y; pb0[2] = (f16)b0.z; pb0[3] = (f16)b0.w;
            pb0[4] = (f16)b1.x; pb0[5] = (f16)b1.y; pb0[6] = (f16)b1.z; pb0[7] = (f16)b1.w;
            pb1[0] = (f16)b2.x; pb1[1] = (f16)b2.y; pb1[2] = (f16)b2.z; pb1[3] = (f16)b2.w;
            pb1[4] = (f16)b3.x; pb1[5] = (f16)b3.y; pb1[6] = (f16)b3.z; pb1[7] = (f16)b3.w;
            *(half8*)&As[srow * KP + skh]     = pa0;
            *(half8*)&As[srow * KP + skh + 8] = pa1;
            *(half8*)&Bs[srow * KP + skh]     = pb0;
            *(half8*)&Bs[srow * KP + skh + 8] = pb1;
        }
        __syncthreads();

        half8 af[4], bf[4];
#pragma unroll
        for (int i = 0; i < 4; ++i)
            af[i] = *(const half8*)&As[(wm + 16 * i + r16) * KP + kg * 8];
#pragma unroll
        for (int j = 0; j < 4; ++j)
            bf[j] = *(const half8*)&Bs[(wn + 16 * j + r16) * KP + kg * 8];
#pragma unroll
        for (int i = 0; i < 4; ++i)
#pragma unroll
            for (int j = 0; j < 4; ++j)
                acc[i][j] = __builtin_amdgcn_mfma_f32_16x16x32_f16(af[i], bf[j], acc[i][j], 0, 0, 0);
    }

    // epilogue: C[bm+wm+16i + kg*4+r][bn+wn+16j + r16] = acc[i][j][r] + bias
#pragma unroll
    for (int j = 0; j < 4; ++j) {
        const int col = bn + wn + 16 * j + r16;
        const float bv = bias[col];
#pragma unroll
        for (int i = 0; i < 4; ++i) {
            const int row0 = bm + wm + 16 * i + kg * 4;
#pragma unroll
            for (int r = 0; r < 4; ++r)
                C[(size_t)(row0 + r) * N + col] = acc[i][j][r] + bv;
        }
    }
}

// ---------------------------------------------------------------------------
// Attention v3 (UNCHANGED from passing round): fp16-pair LDS + v_dot2_f32_f16.
// ---------------------------------------------------------------------------
constexpr int QT = 128;       // queries per block
constexpr int KTILE = 128;    // keys per tile
constexpr int QP2 = 132;      // row stride (f16x2 units) for Qs2/Kt2/WS2
constexpr int VP2 = 68;       // row stride (f16x2 units) for Vt2

constexpr int Q_OFF  = 0;                    // Qs2  32*132 = 4224
constexpr int KV_OFF = 4224;                 // Kt2 32*132=4224 | Vt2 64*68=4352
constexpr int W_OFF  = KV_OFF + 4352;        // WS2 64*132 = 8448
constexpr int COL_OFF = W_OFF + 8448;        // COL fp32 [1024]
constexpr int SMEM_WORDS = COL_OFF + 1024;   // 18048 words = 72192 B

__global__ __launch_bounds__(256, 2)
void attn_kernel(const float* __restrict__ qkv, float* __restrict__ ctx,
                 float* __restrict__ avg_out) {
    __shared__ __align__(16) float smemf[SMEM_WORDS];
    f16x2* Qs2 = (f16x2*)(smemf + Q_OFF);   // [dp][q]
    f16x2* Kt2 = (f16x2*)(smemf + KV_OFF);  // [dp][k]
    f16x2* Vt2 = (f16x2*)(smemf + KV_OFF);  // [kp][d] (union)
    f16x2* WS2 = (f16x2*)(smemf + W_OFF);   // [kp][q]
    float* COL = smemf + COL_OFF;

    const int tid = threadIdx.x;
    const int qt = blockIdx.x;
    const int h  = blockIdx.y;
    const int b  = blockIdx.z;
    const int l0 = qt * QT;
    const size_t rowstride = 3 * Ec;
    const float* base = qkv + (size_t)b * Lc * rowstride + (size_t)h * Dc;

    const int sr = tid >> 1;
    const int sh = (tid & 1) * 32;

    {   // stage Q as d-pairs [dp][q], scaled by 1/sqrt(D)
        const float* src = base + (size_t)(l0 + sr) * rowstride + sh;
#pragma unroll
        for (int jj = 0; jj < 8; ++jj) {
            float4 v = *(const float4*)(src + jj * 4);
            int dp = (sh >> 1) + jj * 2;
            Qs2[(dp + 0) * QP2 + sr] = pack2(v.x * 0.125f, v.y * 0.125f);
            Qs2[(dp + 1) * QP2 + sr] = pack2(v.z * 0.125f, v.w * 0.125f);
        }
    }

    const int ty = tid >> 4;
    const int tx = tid & 15;

    // ================= sweep 1: row sums of exp(scores) =================
    float rs[8];
#pragma unroll
    for (int i = 0; i < 8; ++i) rs[i] = 0.f;

    for (int kt = 0; kt < Lc / KTILE; ++kt) {
        __syncthreads();
        {   // stage K tile as d-pairs [dp][k]
            const float* src = base + (size_t)(kt * KTILE + sr) * rowstride + Ec + sh;
#pragma unroll
            for (int jj = 0; jj < 8; ++jj) {
                float4 v = *(const float4*)(src + jj * 4);
                int dp = (sh >> 1) + jj * 2;
                Kt2[(dp + 0) * QP2 + sr] = pack2(v.x, v.y);
                Kt2[(dp + 1) * QP2 + sr] = pack2(v.z, v.w);
            }
        }
        __syncthreads();

        float acc[8][8];
#pragma unroll
        for (int i = 0; i < 8; ++i)
#pragma unroll
            for (int j = 0; j < 8; ++j) acc[i][j] = 0.f;

#pragma unroll 4
        for (int dp = 0; dp < Dc / 2; ++dp) {
            const f16x2* qrow = Qs2 + dp * QP2;
            const f16x2* krow = Kt2 + dp * QP2;
            H2x4 qa = *(const H2x4*)(qrow + ty * 8);
            H2x4 qb = *(const H2x4*)(qrow + ty * 8 + 4);
            H2x4 ka = *(const H2x4*)(krow + tx * 4);
            H2x4 kb = *(const H2x4*)(krow + 64 + tx * 4);
#pragma unroll
            for (int i = 0; i < 8; ++i) {
                f16x2 q2 = (i < 4) ? qa.v[i] : qb.v[i - 4];
#pragma unroll
                for (int j = 0; j < 8; ++j) {
                    f16x2 k2 = (j < 4) ? ka.v[j] : kb.v[j - 4];
                    acc[i][j] = FDOT2(q2, k2, acc[i][j]);
                }
            }
        }
#pragma unroll
        for (int i = 0; i < 8; ++i) {
            float t = 0.f;
#pragma unroll
            for (int j = 0; j < 8; ++j) t += __expf(acc[i][j]);
            rs[i] += t;
        }
    }

    float rinv[8];
#pragma unroll
    for (int i = 0; i < 8; ++i) {
        float v = rs[i];
        v += __shfl_xor(v, 1);
        v += __shfl_xor(v, 2);
        v += __shfl_xor(v, 4);
        v += __shfl_xor(v, 8);
        rinv[i] = 1.f / v;
    }

    // ================= sweep 2: recompute, normalize, PV, col sums =======
    const int qblk = (tid >> 3) & 15;
    const int dblk = tid & 7;
    const int kh   = tid >> 7;

    float cacc[8][8];
#pragma unroll
    for (int i = 0; i < 8; ++i)
#pragma unroll
        for (int j = 0; j < 8; ++j) cacc[i][j] = 0.f;

    for (int kt = 0; kt < Lc / KTILE; ++kt) {
        __syncthreads();
        {   // stage K tile as d-pairs [dp][k]
            const float* src = base + (size_t)(kt * KTILE + sr) * rowstride + Ec + sh;
#pragma unroll
            for (int jj = 0; jj < 8; ++jj) {
                float4 v = *(const float4*)(src + jj * 4);
                int dp = (sh >> 1) + jj * 2;
                Kt2[(dp + 0) * QP2 + sr] = pack2(v.x, v.y);
                Kt2[(dp + 1) * QP2 + sr] = pack2(v.z, v.w);
            }
        }
        __syncthreads();

        float acc[8][8];
#pragma unroll
        for (int i = 0; i < 8; ++i)
#pragma unroll
            for (int j = 0; j < 8; ++j) acc[i][j] = 0.f;

#pragma unroll 4
        for (int dp = 0; dp < Dc / 2; ++dp) {
            const f16x2* qrow = Qs2 + dp * QP2;
            const f16x2* krow = Kt2 + dp * QP2;
            H2x4 qa = *(const H2x4*)(qrow + ty * 8);
            H2x4 qb = *(const H2x4*)(qrow + ty * 8 + 4);
            H2x4 ka = *(const H2x4*)(krow + tx * 4);
            H2x4 kb = *(const H2x4*)(krow + 64 + tx * 4);
#pragma unroll
            for (int i = 0; i < 8; ++i) {
                f16x2 q2 = (i < 4) ? qa.v[i] : qb.v[i - 4];
#pragma unroll
                for (int j = 0; j < 8; ++j) {
                    f16x2 k2 = (j < 4) ? ka.v[j] : kb.v[j - 4];
                    acc[i][j] = FDOT2(q2, k2, acc[i][j]);
                }
            }
        }

#pragma unroll
        for (int i = 0; i < 8; ++i)
#pragma unroll
            for (int j = 0; j < 8; ++j) acc[i][j] = __expf(acc[i][j]) * rinv[i];

        // pack w into k-pair fp16 and write WS2[kp][q]
#pragma unroll
        for (int j = 0; j < 2; ++j) {
            {
                f16x2* dst = WS2 + (2 * tx + j) * QP2 + ty * 8;
#pragma unroll
                for (int i = 0; i < 8; ++i) dst[i] = pack2(acc[i][2 * j], acc[i][2 * j + 1]);
            }
            {
                f16x2* dst = WS2 + (32 + 2 * tx + j) * QP2 + ty * 8;
#pragma unroll
                for (int i = 0; i < 8; ++i) dst[i] = pack2(acc[i][4 + 2 * j], acc[i][5 + 2 * j]);
            }
        }
        __syncthreads();

        {   // stage V tile k-pair interleaved: Vt2[kp][d] = {V[2kp][d], V[2kp+1][d]}
            int kp = tid >> 2;
            int dq = (tid & 3) * 16;
            const float* s0 = base + (size_t)(kt * KTILE + 2 * kp) * rowstride + 2 * Ec + dq;
            const float* s1 = s0 + rowstride;
            f16x2* dst = Vt2 + kp * VP2 + dq;
#pragma unroll
            for (int jj = 0; jj < 4; ++jj) {
                float4 a = *(const float4*)(s0 + jj * 4);
                float4 bb = *(const float4*)(s1 + jj * 4);
                dst[jj * 4 + 0] = pack2(a.x, bb.x);
                dst[jj * 4 + 1] = pack2(a.y, bb.y);
                dst[jj * 4 + 2] = pack2(a.z, bb.z);
                dst[jj * 4 + 3] = pack2(a.w, bb.w);
            }
        }
        __syncthreads();

        // PV: ctx[8q][8d] += w2[q][kp] . v2[kp][d]
#pragma unroll 4
        for (int kp = 0; kp < 32; ++kp) {
            int kk = kh * 32 + kp;
            const f16x2* wrow = WS2 + kk * QP2 + qblk * 8;
            const f16x2* vrow = Vt2 + kk * VP2 + dblk * 8;
            H2x4 wa = *(const H2x4*)(wrow);
            H2x4 wb = *(const H2x4*)(wrow + 4);
            H2x4 va = *(const H2x4*)(vrow);
            H2x4 vb = *(const H2x4*)(vrow + 4);
#pragma unroll
            for (int i = 0; i < 8; ++i) {
                f16x2 w2 = (i < 4) ? wa.v[i] : wb.v[i - 4];
#pragma unroll
                for (int j = 0; j < 8; ++j) {
                    f16x2 v2 = (j < 4) ? va.v[j] : vb.v[j - 4];
                    cacc[i][j] = FDOT2(w2, v2, cacc[i][j]);
                }
            }
        }

        // column sums of w (for avg_attn)
        {
            int kpc = tid >> 2;
            int qq = tid & 3;
            const f16x2* wr = WS2 + kpc * QP2 + qq * 32;
            float sx = 0.f, sy = 0.f;
#pragma unroll
            for (int t = 0; t < 8; ++t) {
                H2x4 w = *(const H2x4*)(wr + t * 4);
#pragma unroll
                for (int c = 0; c < 4; ++c) {
                    sx += (float)w.v[c][0];
                    sy += (float)w.v[c][1];
                }
            }
            sx += __shfl_xor(sx, 1); sx += __shfl_xor(sx, 2);
            sy += __shfl_xor(sy, 1); sy += __shfl_xor(sy, 2);
            if (qq == 0) {
                COL[kt * KTILE + 2 * kpc]     = sx;
                COL[kt * KTILE + 2 * kpc + 1] = sy;
            }
        }
    }

    // ---- epilogue: combine k-halves, write ctx ----
    __syncthreads();
    float* red = smemf + W_OFF;
    if (kh == 1) {
        float* slot = red + (tid & 127) * 64;
#pragma unroll
        for (int i = 0; i < 8; ++i) {
            float4 c0 = {cacc[i][0], cacc[i][1], cacc[i][2], cacc[i][3]};
            float4 c1 = {cacc[i][4], cacc[i][5], cacc[i][6], cacc[i][7]};
            *(float4*)(slot + i * 8)     = c0;
            *(float4*)(slot + i * 8 + 4) = c1;
        }
    }
    __syncthreads();
    if (kh == 0) {
        float* slot = red + tid * 64;
#pragma unroll
        for (int i = 0; i < 8; ++i) {
            float4 o0 = *(const float4*)(slot + i * 8);
            float4 o1 = *(const float4*)(slot + i * 8 + 4);
            float4 c0 = {cacc[i][0] + o0.x, cacc[i][1] + o0.y, cacc[i][2] + o0.z, cacc[i][3] + o0.w};
            float4 c1 = {cacc[i][4] + o1.x, cacc[i][5] + o1.y, cacc[i][6] + o1.z, cacc[i][7] + o1.w};
            float* dst = ctx + (size_t)(b * Lc + l0 + qblk * 8 + i) * Ec + h * Dc + dblk * 8;
            *(float4*)(dst)     = c0;
            *(float4*)(dst + 4) = c1;
        }
    }

    __syncthreads();
#pragma unroll
    for (int t = 0; t < 4; ++t) {
        int m = t * 256 + tid;
        atomicAdd(&avg_out[b * Lc + m], COL[m] * (1.0f / (Hc * Lc)));
    }
}

// ---------------------------------------------------------------------------
// LayerNorm stats: one block per (b,l) row. h = x + attn_out.  (UNCHANGED)
// ---------------------------------------------------------------------------
__global__ __launch_bounds__(256)
void stats_kernel(const float* __restrict__ x, const float* __restrict__ attn_out,
                  float2* __restrict__ stats) {
    const int row = blockIdx.x;
    const int tid = threadIdx.x;
    const float* xp = x + (size_t)row * Ec;
    const float* ap = attn_out + (size_t)row * Ec;
    float4 xv = *(const float4*)(xp + tid * 4);
    float4 av = *(const float4*)(ap + tid * 4);
    float h0 = xv.x + av.x, h1 = xv.y + av.y, h2 = xv.z + av.z, h3 = xv.w + av.w;
    float s = h0 + h1 + h2 + h3;
    float ss = h0 * h0 + h1 * h1 + h2 * h2 + h3 * h3;
#pragma unroll
    for (int off = 32; off; off >>= 1) {
        s += __shfl_xor(s, off);
        ss += __shfl_xor(ss, off);
    }
    __shared__ float wsum[4], wsq[4];
    const int wave = tid >> 6, lane = tid & 63;
    if (lane == 0) { wsum[wave] = s; wsq[wave] = ss; }
    __syncthreads();
    if (tid == 0) {
        float ts = wsum[0] + wsum[1] + wsum[2] + wsum[3];
        float tq = wsq[0] + wsq[1] + wsq[2] + wsq[3];
        float mean = ts * (1.0f / Ec);
        float var = tq * (1.0f / Ec) - mean * mean;
        stats[row] = make_float2(mean, rsqrtf(var + EPSc));
    }
}

// ---------------------------------------------------------------------------
// Pooled output: pooled[b][f] = mean_l( (h-mu)*rstd*gamma[f] + beta[f] )  (UNCHANGED)
// ---------------------------------------------------------------------------
__global__ __launch_bounds__(256)
void pool_kernel(const float* __restrict__ x, const float* __restrict__ attn_out,
                 const float2* __restrict__ stats, const float* __restrict__ gamma,
                 const float* __restrict__ beta, float* __restrict__ pooled) {
    const int b = blockIdx.z;
    const int f = blockIdx.y * 256 + threadIdx.x;
    const int l0 = blockIdx.x * 64;
    const float g = gamma[f];
    const float be = beta[f];
    float acc = 0.f;
    for (int l = l0; l < l0 + 64; ++l) {
        size_t idx = (size_t)(b * Lc + l) * Ec + f;
        float2 st = stats[b * Lc + l];
        float h = x[idx] + attn_out[idx];
        acc += (h - st.x) * st.y * g + be;
    }
    atomicAdd(&pooled[b * Ec + f], acc * (1.0f / Lc));
}

// ---------------------------------------------------------------------------
extern "C" void kernel_launch(void* const* d_in, const int* in_sizes, int n_in,
                              void* d_out, int out_size, void* d_ws, size_t ws_size,
                              hipStream_t stream) {
    const float* x      = (const float*)d_in[0];   // (B,L,E)
    const float* w_qkv  = (const float*)d_in[1];   // (3E,E)
    const float* b_qkv  = (const float*)d_in[2];   // (3E,)
    const float* w_out  = (const float*)d_in[3];   // (E,E)
    const float* b_out  = (const float*)d_in[4];   // (E,)
    const float* gamma  = (const float*)d_in[5];   // (E,)
    const float* beta   = (const float*)d_in[6];   // (E,)
    float* out = (float*)d_out;                    // pooled (B,E) then avg_attn (B,L)

    // workspace layout (floats): qkv 25165824 | ctx 8388608 | stats 16384
    float* qkv   = (float*)d_ws;
    float* ctx   = qkv + (size_t)Bc * Lc * 3 * Ec;
    float* stats = ctx + (size_t)Bc * Lc * Ec;
    float* attn_out = qkv;   // reuse: qkv dead after attention

    const int M = Bc * Lc;   // 8192

    hipMemsetAsync(d_out, 0, (size_t)out_size * sizeof(float), stream);

    // 1) QKV projection: (8192 x 1024) x (3072 x 1024)^T
    dim3 g1(M / 128, (3 * Ec) / 128);
    gemm_nt<<<g1, 256, 0, stream>>>(x, w_qkv, b_qkv, qkv, M, 3 * Ec, Ec);

    // 2) attention + avg_attn
    dim3 g2(Lc / QT, Hc, Bc);
    attn_kernel<<<g2, 256, 0, stream>>>(qkv, ctx, out + Bc * Ec);

    // 3) output projection: (8192 x 1024) x (1024 x 1024)^T  (writes over qkv)
    dim3 g3(M / 128, Ec / 128);
    gemm_nt<<<g3, 256, 0, stream>>>(ctx, w_out, b_out, attn_out, M, Ec, Ec);

    // 4) LN stats
    stats_kernel<<<M, 256, 0, stream>>>(x, attn_out, (float2*)stats);

    // 5) pooled
    dim3 g5(16, 4, Bc);
    pool_kernel<<<g5, 256, 0, stream>>>(x, attn_out, (float2*)stats, gamma, beta, out);
}

// Round 5
// 430.938 us; speedup vs baseline: 8.2181x; 1.7307x over previous
//
#include <hip/hip_runtime.h>
#include <math.h>

// Problem constants (B,L,E,H,D) = (8,1024,1024,16,64)
constexpr int Bc = 8;
constexpr int Lc = 1024;
constexpr int Ec = 1024;
constexpr int Hc = 16;
constexpr int Dc = 64;
constexpr float EPSc = 1e-5f;

// ---- fp16 types ----
typedef _Float16 f16;
typedef f16 half8 __attribute__((ext_vector_type(8)));
typedef float floatx4 __attribute__((ext_vector_type(4)));

// ---------------------------------------------------------------------------
// GEMM (MFMA fp16): C[M][N] = sum_k A[M][K]*B[N][K] + bias[N], fp32 accum.
// 128x128 tile, 4 waves 2x2, each 64x64 (4x4 MFMA 16x16), KT=32. (UNCHANGED)
// ---------------------------------------------------------------------------
__global__ __launch_bounds__(256)
void gemm_nt(const float* __restrict__ A, const float* __restrict__ Bm,
             const float* __restrict__ bias, float* __restrict__ C,
             int M, int N, int K) {
    constexpr int TILE = 128;
    constexpr int KT = 32;
    constexpr int KP = 40;                 // padded row length in f16
    __shared__ f16 As[TILE * KP];          // 10240 B
    __shared__ f16 Bs[TILE * KP];          // 10240 B

    const int tid = threadIdx.x;
    const int bm = blockIdx.x * TILE;
    const int bn = blockIdx.y * TILE;

    const int wave = tid >> 6;
    const int lane = tid & 63;
    const int wm = (wave >> 1) * 64;
    const int wn = (wave & 1) * 64;
    const int r16 = lane & 15;
    const int kg = lane >> 4;

    floatx4 acc[4][4];
#pragma unroll
    for (int i = 0; i < 4; ++i)
#pragma unroll
        for (int j = 0; j < 4; ++j) acc[i][j] = (floatx4){0.f, 0.f, 0.f, 0.f};

    const int srow = tid >> 1;
    const int skh = (tid & 1) * 16;
    const float* aptr = A + (size_t)(bm + srow) * K + skh;
    const float* bptr = Bm + (size_t)(bn + srow) * K + skh;

    for (int k0 = 0; k0 < K; k0 += KT) {
        float4 a0 = *(const float4*)(aptr + k0);
        float4 a1 = *(const float4*)(aptr + k0 + 4);
        float4 a2 = *(const float4*)(aptr + k0 + 8);
        float4 a3 = *(const float4*)(aptr + k0 + 12);
        float4 b0 = *(const float4*)(bptr + k0);
        float4 b1 = *(const float4*)(bptr + k0 + 4);
        float4 b2 = *(const float4*)(bptr + k0 + 8);
        float4 b3 = *(const float4*)(bptr + k0 + 12);
        __syncthreads();
        {
            half8 pa0, pa1, pb0, pb1;
            pa0[0] = (f16)a0.x; pa0[1] = (f16)a0.y; pa0[2] = (f16)a0.z; pa0[3] = (f16)a0.w;
            pa0[4] = (f16)a1.x; pa0[5] = (f16)a1.y; pa0[6] = (f16)a1.z; pa0[7] = (f16)a1.w;
            pa1[0] = (f16)a2.x; pa1[1] = (f16)a2.y; pa1[2] = (f16)a2.z; pa1[3] = (f16)a2.w;
            pa1[4] = (f16)a3.x; pa1[5] = (f16)a3.y; pa1[6] = (f16)a3.z; pa1[7] = (f16)a3.w;
            pb0[0] = (f16)b0.x; pb0[1] = (f16)b0.y; pb0[2] = (f16)b0.z; pb0[3] = (f16)b0.w;
            pb0[4] = (f16)b1.x; pb0[5] = (f16)b1.y; pb0[6] = (f16)b1.z; pb0[7] = (f16)b1.w;
            pb1[0] = (f16)b2.x; pb1[1] = (f16)b2.y; pb1[2] = (f16)b2.z; pb1[3] = (f16)b2.w;
            pb1[4] = (f16)b3.x; pb1[5] = (f16)b3.y; pb1[6] = (f16)b3.z; pb1[7] = (f16)b3.w;
            *(half8*)&As[srow * KP + skh]     = pa0;
            *(half8*)&As[srow * KP + skh + 8] = pa1;
            *(half8*)&Bs[srow * KP + skh]     = pb0;
            *(half8*)&Bs[srow * KP + skh + 8] = pb1;
        }
        __syncthreads();

        half8 af[4], bf[4];
#pragma unroll
        for (int i = 0; i < 4; ++i)
            af[i] = *(const half8*)&As[(wm + 16 * i + r16) * KP + kg * 8];
#pragma unroll
        for (int j = 0; j < 4; ++j)
            bf[j] = *(const half8*)&Bs[(wn + 16 * j + r16) * KP + kg * 8];
#pragma unroll
        for (int i = 0; i < 4; ++i)
#pragma unroll
            for (int j = 0; j < 4; ++j)
                acc[i][j] = __builtin_amdgcn_mfma_f32_16x16x32_f16(af[i], bf[j], acc[i][j], 0, 0, 0);
    }

#pragma unroll
    for (int j = 0; j < 4; ++j) {
        const int col = bn + wn + 16 * j + r16;
        const float bv = bias[col];
#pragma unroll
        for (int i = 0; i < 4; ++i) {
            const int row0 = bm + wm + 16 * i + kg * 4;
#pragma unroll
            for (int r = 0; r < 4; ++r)
                C[(size_t)(row0 + r) * N + col] = acc[i][j][r] + bv;
        }
    }
}

// ---------------------------------------------------------------------------
// Attention v4 (MFMA): one block per (b,h,128q), 256 threads = 4 waves.
// No-max softmax. Sweep 1: QK^T (MFMA) -> exp -> row sums (regs+shfl+ds_add).
// Sweep 2: QK^T (MFMA) -> w = exp*rinv -> WS[q][k] fp16 + in-reg col sums;
//          stage V^T [d][k]; PV via MFMA; ctx from accum frags.
// Fragment maps identical to gemm_nt (HW-validated this session).
// LDS 74.5 KB -> 2 blocks/CU.
// ---------------------------------------------------------------------------
constexpr int AQT = 128;     // queries per block
constexpr int AKT = 128;     // keys per tile
constexpr int AKP = 72;      // f16 row stride for Kq/Kt [row][d]   (144 B)
constexpr int AWP = 136;     // f16 row stride for WS   [q][k]     (272 B)
constexpr int AVP = 136;     // f16 row stride for Vt   [d][k]     (272 B)

// word (4B) offsets
constexpr int AQ_OFF  = 0;                   // Kq 128*72 f16  = 4608 w
constexpr int AKV_OFF = 4608;                // Kt 4608 w | Vt 64*136 f16 = 4352 w
constexpr int AW_OFF  = AKV_OFF + 4608;      // WS 128*136 f16 = 8704 w
constexpr int ARS_OFF = AW_OFF + 8704;       // RS fp32 [128]
constexpr int ACOL_OFF = ARS_OFF + 128;      // COL fp32 [1024]
constexpr int ASMEM   = ACOL_OFF + 1024;     // 19072 w = 76288 B

static __device__ inline void stage_row_f16(const float* __restrict__ src,
                                            f16* __restrict__ dst, float scale) {
#pragma unroll
    for (int jj = 0; jj < 4; ++jj) {
        float4 a = *(const float4*)(src + jj * 8);
        float4 b = *(const float4*)(src + jj * 8 + 4);
        half8 p;
        p[0] = (f16)(a.x * scale); p[1] = (f16)(a.y * scale);
        p[2] = (f16)(a.z * scale); p[3] = (f16)(a.w * scale);
        p[4] = (f16)(b.x * scale); p[5] = (f16)(b.y * scale);
        p[6] = (f16)(b.z * scale); p[7] = (f16)(b.w * scale);
        *(half8*)(dst + jj * 8) = p;
    }
}

__global__ __launch_bounds__(256, 2)
void attn_kernel(const float* __restrict__ qkv, float* __restrict__ ctx,
                 float* __restrict__ avg_out) {
    __shared__ __align__(16) float smemf[ASMEM];
    f16* Kq = (f16*)(smemf + AQ_OFF);    // [q][d]  (pre-scaled by 0.125)
    f16* Kt = (f16*)(smemf + AKV_OFF);   // [k][d]
    f16* Vt = (f16*)(smemf + AKV_OFF);   // [d][k]  (union with Kt)
    f16* WS = (f16*)(smemf + AW_OFF);    // [q][k]  normalized w
    float* RS  = smemf + ARS_OFF;        // row sums -> rinv
    float* COL = smemf + ACOL_OFF;       // col sums of w

    const int tid = threadIdx.x;
    const int qt = blockIdx.x, h = blockIdx.y, b = blockIdx.z;
    const int l0 = qt * AQT;
    const size_t rowstride = 3 * Ec;
    const float* base = qkv + (size_t)b * Lc * rowstride + (size_t)h * Dc;

    const int wave = tid >> 6, lane = tid & 63;
    const int r16 = lane & 15, kg = lane >> 4;
    const int wm = (wave >> 1) * 64;     // QK^T quadrant q-origin
    const int wn = (wave & 1) * 64;      // QK^T quadrant k-origin

    if (tid < 128) RS[tid] = 0.f;
#pragma unroll
    for (int t = 0; t < 4; ++t) COL[t * 256 + tid] = 0.f;

    const int srow = tid >> 1;           // staging row (0..127)
    const int sh = (tid & 1) * 32;       // staging col-half

    // stage Q (scaled by 1/sqrt(D))
    stage_row_f16(base + (size_t)(l0 + srow) * rowstride + sh, Kq + srow * AKP + sh, 0.125f);

    // ================= sweep 1: row sums of exp(scores) =================
    float rs[4][4];
#pragma unroll
    for (int i = 0; i < 4; ++i)
#pragma unroll
        for (int r = 0; r < 4; ++r) rs[i][r] = 0.f;

    for (int kt = 0; kt < Lc / AKT; ++kt) {
        __syncthreads();
        stage_row_f16(base + (size_t)(kt * AKT + srow) * rowstride + Ec + sh,
                      Kt + srow * AKP + sh, 1.0f);
        __syncthreads();

        floatx4 s[4][4];
#pragma unroll
        for (int i = 0; i < 4; ++i)
#pragma unroll
            for (int j = 0; j < 4; ++j) s[i][j] = (floatx4){0.f, 0.f, 0.f, 0.f};
#pragma unroll
        for (int ks = 0; ks < 2; ++ks) {
            half8 af[4], bf[4];
#pragma unroll
            for (int i = 0; i < 4; ++i)
                af[i] = *(const half8*)&Kq[(wm + 16 * i + r16) * AKP + ks * 32 + kg * 8];
#pragma unroll
            for (int j = 0; j < 4; ++j)
                bf[j] = *(const half8*)&Kt[(wn + 16 * j + r16) * AKP + ks * 32 + kg * 8];
#pragma unroll
            for (int i = 0; i < 4; ++i)
#pragma unroll
                for (int j = 0; j < 4; ++j)
                    s[i][j] = __builtin_amdgcn_mfma_f32_16x16x32_f16(af[i], bf[j], s[i][j], 0, 0, 0);
        }
#pragma unroll
        for (int i = 0; i < 4; ++i)
#pragma unroll
            for (int r = 0; r < 4; ++r)
                rs[i][r] += __expf(s[i][0][r]) + __expf(s[i][1][r]) +
                            __expf(s[i][2][r]) + __expf(s[i][3][r]);
    }

    // reduce over the 16 col-lanes, combine wave pairs via LDS atomics
#pragma unroll
    for (int i = 0; i < 4; ++i)
#pragma unroll
        for (int r = 0; r < 4; ++r) {
            float v = rs[i][r];
            v += __shfl_xor(v, 1); v += __shfl_xor(v, 2);
            v += __shfl_xor(v, 4); v += __shfl_xor(v, 8);
            rs[i][r] = v;
        }
    if (r16 == 0) {
#pragma unroll
        for (int i = 0; i < 4; ++i)
#pragma unroll
            for (int r = 0; r < 4; ++r)
                atomicAdd(&RS[wm + 16 * i + 4 * kg + r], rs[i][r]);
    }
    __syncthreads();
    if (tid < 128) RS[tid] = 1.0f / RS[tid];
    __syncthreads();

    float rinv[4][4];
#pragma unroll
    for (int i = 0; i < 4; ++i)
#pragma unroll
        for (int r = 0; r < 4; ++r) rinv[i][r] = RS[wm + 16 * i + 4 * kg + r];

    // ================= sweep 2: w -> WS, col sums, PV =================
    floatx4 cacc[2][4];
#pragma unroll
    for (int p = 0; p < 2; ++p)
#pragma unroll
        for (int j = 0; j < 4; ++j) cacc[p][j] = (floatx4){0.f, 0.f, 0.f, 0.f};
    const int qb = wave * 32;            // PV q-origin for this wave

    for (int kt = 0; kt < Lc / AKT; ++kt) {
        __syncthreads();                  // prev PV reads of Vt/WS done
        stage_row_f16(base + (size_t)(kt * AKT + srow) * rowstride + Ec + sh,
                      Kt + srow * AKP + sh, 1.0f);
        __syncthreads();

        floatx4 s[4][4];
#pragma unroll
        for (int i = 0; i < 4; ++i)
#pragma unroll
            for (int j = 0; j < 4; ++j) s[i][j] = (floatx4){0.f, 0.f, 0.f, 0.f};
#pragma unroll
        for (int ks = 0; ks < 2; ++ks) {
            half8 af[4], bf[4];
#pragma unroll
            for (int i = 0; i < 4; ++i)
                af[i] = *(const half8*)&Kq[(wm + 16 * i + r16) * AKP + ks * 32 + kg * 8];
#pragma unroll
            for (int j = 0; j < 4; ++j)
                bf[j] = *(const half8*)&Kt[(wn + 16 * j + r16) * AKP + ks * 32 + kg * 8];
#pragma unroll
            for (int i = 0; i < 4; ++i)
#pragma unroll
                for (int j = 0; j < 4; ++j)
                    s[i][j] = __builtin_amdgcn_mfma_f32_16x16x32_f16(af[i], bf[j], s[i][j], 0, 0, 0);
        }

        // w = exp(s)*rinv; per-lane col partials
        float cs[4] = {0.f, 0.f, 0.f, 0.f};
#pragma unroll
        for (int i = 0; i < 4; ++i)
#pragma unroll
            for (int j = 0; j < 4; ++j)
#pragma unroll
                for (int r = 0; r < 4; ++r) {
                    float w = __expf(s[i][j][r]) * rinv[i][r];
                    s[i][j][r] = w;
                    cs[j] += w;
                }

        __syncthreads();                  // all Kt reads done -> Vt may overwrite

        // write w to WS[q][k]
#pragma unroll
        for (int i = 0; i < 4; ++i)
#pragma unroll
            for (int r = 0; r < 4; ++r) {
                f16* wrow = WS + (wm + 16 * i + 4 * kg + r) * AWP + wn + r16;
#pragma unroll
                for (int j = 0; j < 4; ++j) wrow[16 * j] = (f16)s[i][j][r];
            }

        // stage V^T: Vt[d][k]
        {
            const float* src = base + (size_t)(kt * AKT + srow) * rowstride + 2 * Ec + sh;
#pragma unroll
            for (int jj = 0; jj < 8; ++jj) {
                float4 v = *(const float4*)(src + jj * 4);
                int d0 = sh + jj * 4;
                Vt[(d0 + 0) * AVP + srow] = (f16)v.x;
                Vt[(d0 + 1) * AVP + srow] = (f16)v.y;
                Vt[(d0 + 2) * AVP + srow] = (f16)v.z;
                Vt[(d0 + 3) * AVP + srow] = (f16)v.w;
            }
        }

        // col sums -> COL (reduce over the 4 row-groups, lanes kg==0 commit)
#pragma unroll
        for (int j = 0; j < 4; ++j) {
            float c = cs[j];
            c += __shfl_xor(c, 16);
            c += __shfl_xor(c, 32);
            if (kg == 0) atomicAdd(&COL[kt * AKT + wn + 16 * j + r16], c);
        }

        __syncthreads();                  // WS & Vt ready

        // PV: wave owns q rows qb..qb+31, all 64 d
#pragma unroll
        for (int ks2 = 0; ks2 < 4; ++ks2) {
            half8 wa[2], vb[4];
#pragma unroll
            for (int p = 0; p < 2; ++p)
                wa[p] = *(const half8*)&WS[(qb + 16 * p + r16) * AWP + ks2 * 32 + kg * 8];
#pragma unroll
            for (int j = 0; j < 4; ++j)
                vb[j] = *(const half8*)&Vt[(16 * j + r16) * AVP + ks2 * 32 + kg * 8];
#pragma unroll
            for (int p = 0; p < 2; ++p)
#pragma unroll
                for (int j = 0; j < 4; ++j)
                    cacc[p][j] = __builtin_amdgcn_mfma_f32_16x16x32_f16(wa[p], vb[j], cacc[p][j], 0, 0, 0);
        }
    }

    // ---- epilogue: ctx from accumulator fragments ----
#pragma unroll
    for (int p = 0; p < 2; ++p)
#pragma unroll
        for (int r = 0; r < 4; ++r) {
            float* dst = ctx + (size_t)(b * Lc + l0 + qb + 16 * p + 4 * kg + r) * Ec + h * Dc + r16;
#pragma unroll
            for (int j = 0; j < 4; ++j) dst[16 * j] = cacc[p][j][r];
        }

    // ---- flush avg_attn ----
    __syncthreads();
#pragma unroll
    for (int t = 0; t < 4; ++t) {
        int m = t * 256 + tid;
        atomicAdd(&avg_out[b * Lc + m], COL[m] * (1.0f / (Hc * Lc)));
    }
}

// ---------------------------------------------------------------------------
// LayerNorm stats: one block per (b,l) row. h = x + attn_out.  (UNCHANGED)
// ---------------------------------------------------------------------------
__global__ __launch_bounds__(256)
void stats_kernel(const float* __restrict__ x, const float* __restrict__ attn_out,
                  float2* __restrict__ stats) {
    const int row = blockIdx.x;
    const int tid = threadIdx.x;
    const float* xp = x + (size_t)row * Ec;
    const float* ap = attn_out + (size_t)row * Ec;
    float4 xv = *(const float4*)(xp + tid * 4);
    float4 av = *(const float4*)(ap + tid * 4);
    float h0 = xv.x + av.x, h1 = xv.y + av.y, h2 = xv.z + av.z, h3 = xv.w + av.w;
    float s = h0 + h1 + h2 + h3;
    float ss = h0 * h0 + h1 * h1 + h2 * h2 + h3 * h3;
#pragma unroll
    for (int off = 32; off; off >>= 1) {
        s += __shfl_xor(s, off);
        ss += __shfl_xor(ss, off);
    }
    __shared__ float wsum[4], wsq[4];
    const int wave = tid >> 6, lane = tid & 63;
    if (lane == 0) { wsum[wave] = s; wsq[wave] = ss; }
    __syncthreads();
    if (tid == 0) {
        float ts = wsum[0] + wsum[1] + wsum[2] + wsum[3];
        float tq = wsq[0] + wsq[1] + wsq[2] + wsq[3];
        float mean = ts * (1.0f / Ec);
        float var = tq * (1.0f / Ec) - mean * mean;
        stats[row] = make_float2(mean, rsqrtf(var + EPSc));
    }
}

// ---------------------------------------------------------------------------
// Pooled output: pooled[b][f] = mean_l( (h-mu)*rstd*gamma[f] + beta[f] )  (UNCHANGED)
// ---------------------------------------------------------------------------
__global__ __launch_bounds__(256)
void pool_kernel(const float* __restrict__ x, const float* __restrict__ attn_out,
                 const float2* __restrict__ stats, const float* __restrict__ gamma,
                 const float* __restrict__ beta, float* __restrict__ pooled) {
    const int b = blockIdx.z;
    const int f = blockIdx.y * 256 + threadIdx.x;
    const int l0 = blockIdx.x * 64;
    const float g = gamma[f];
    const float be = beta[f];
    float acc = 0.f;
    for (int l = l0; l < l0 + 64; ++l) {
        size_t idx = (size_t)(b * Lc + l) * Ec + f;
        float2 st = stats[b * Lc + l];
        float h = x[idx] + attn_out[idx];
        acc += (h - st.x) * st.y * g + be;
    }
    atomicAdd(&pooled[b * Ec + f], acc * (1.0f / Lc));
}

// ---------------------------------------------------------------------------
extern "C" void kernel_launch(void* const* d_in, const int* in_sizes, int n_in,
                              void* d_out, int out_size, void* d_ws, size_t ws_size,
                              hipStream_t stream) {
    const float* x      = (const float*)d_in[0];   // (B,L,E)
    const float* w_qkv  = (const float*)d_in[1];   // (3E,E)
    const float* b_qkv  = (const float*)d_in[2];   // (3E,)
    const float* w_out  = (const float*)d_in[3];   // (E,E)
    const float* b_out  = (const float*)d_in[4];   // (E,)
    const float* gamma  = (const float*)d_in[5];   // (E,)
    const float* beta   = (const float*)d_in[6];   // (E,)
    float* out = (float*)d_out;                    // pooled (B,E) then avg_attn (B,L)

    // workspace layout (floats): qkv 25165824 | ctx 8388608 | stats 16384
    float* qkv   = (float*)d_ws;
    float* ctx   = qkv + (size_t)Bc * Lc * 3 * Ec;
    float* stats = ctx + (size_t)Bc * Lc * Ec;
    float* attn_out = qkv;   // reuse: qkv dead after attention

    const int M = Bc * Lc;   // 8192

    hipMemsetAsync(d_out, 0, (size_t)out_size * sizeof(float), stream);

    // 1) QKV projection: (8192 x 1024) x (3072 x 1024)^T
    dim3 g1(M / 128, (3 * Ec) / 128);
    gemm_nt<<<g1, 256, 0, stream>>>(x, w_qkv, b_qkv, qkv, M, 3 * Ec, Ec);

    // 2) attention + avg_attn
    dim3 g2(Lc / AQT, Hc, Bc);
    attn_kernel<<<g2, 256, 0, stream>>>(qkv, ctx, out + Bc * Ec);

    // 3) output projection: (8192 x 1024) x (1024 x 1024)^T  (writes over qkv)
    dim3 g3(M / 128, Ec / 128);
    gemm_nt<<<g3, 256, 0, stream>>>(ctx, w_out, b_out, attn_out, M, Ec, Ec);

    // 4) LN stats
    stats_kernel<<<M, 256, 0, stream>>>(x, attn_out, (float2*)stats);

    // 5) pooled
    dim3 g5(16, 4, Bc);
    pool_kernel<<<g5, 256, 0, stream>>>(x, attn_out, (float2*)stats, gamma, beta, out);
}

// Round 6
// 355.513 us; speedup vs baseline: 9.9616x; 1.2122x over previous
//
#include <hip/hip_runtime.h>
#include <math.h>

// Problem constants (B,L,E,H,D) = (8,1024,1024,16,64)
constexpr int Bc = 8;
constexpr int Lc = 1024;
constexpr int Ec = 1024;
constexpr int Hc = 16;
constexpr int Dc = 64;
constexpr float EPSc = 1e-5f;

// ---- fp16 types ----
typedef _Float16 f16;
typedef f16 half8 __attribute__((ext_vector_type(8)));
typedef float floatx4 __attribute__((ext_vector_type(4)));

// ---------------------------------------------------------------------------
// fp32 -> fp16 conversion (one-time). n8 = elems/8.
// ---------------------------------------------------------------------------
__global__ __launch_bounds__(256)
void cvt_f32_f16_kernel(const float* __restrict__ src, f16* __restrict__ dst, int n8) {
    int i = blockIdx.x * 256 + threadIdx.x;
    const int stride = gridDim.x * 256;
    for (; i < n8; i += stride) {
        float4 a = *(const float4*)(src + (size_t)i * 8);
        float4 b = *(const float4*)(src + (size_t)i * 8 + 4);
        half8 p;
        p[0] = (f16)a.x; p[1] = (f16)a.y; p[2] = (f16)a.z; p[3] = (f16)a.w;
        p[4] = (f16)b.x; p[5] = (f16)b.y; p[6] = (f16)b.z; p[7] = (f16)b.w;
        *(half8*)(dst + (size_t)i * 8) = p;
    }
}

// ---------------------------------------------------------------------------
// GEMM (MFMA fp16 in, fp16 or fp32 out): C = A * B^T + bias.
// A[M][K], B[N][K] fp16, K-contiguous. 128x128 tile, 4 waves 2x2 (64x64 each,
// 4x4 MFMA 16x16x32), KT=32. LDS rows padded to 40 f16 -> 2-way banks (free).
// Staging is pure 16B copies (inputs already fp16).
// ---------------------------------------------------------------------------
__global__ __launch_bounds__(256)
void gemm_nt_h(const f16* __restrict__ A, const f16* __restrict__ Bm,
               const float* __restrict__ bias, float* __restrict__ Cf,
               f16* __restrict__ Ch, int M, int N, int K) {
    constexpr int TILE = 128;
    constexpr int KT = 32;
    constexpr int KP = 40;
    __shared__ f16 As[TILE * KP];
    __shared__ f16 Bs[TILE * KP];

    const int tid = threadIdx.x;
    const int bm = blockIdx.x * TILE;
    const int bn = blockIdx.y * TILE;

    const int wave = tid >> 6;
    const int lane = tid & 63;
    const int wm = (wave >> 1) * 64;
    const int wn = (wave & 1) * 64;
    const int r16 = lane & 15;
    const int kg = lane >> 4;

    floatx4 acc[4][4];
#pragma unroll
    for (int i = 0; i < 4; ++i)
#pragma unroll
        for (int j = 0; j < 4; ++j) acc[i][j] = (floatx4){0.f, 0.f, 0.f, 0.f};

    const int srow = tid >> 1;            // 0..127
    const int skh = (tid & 1) * 16;       // f16 offset 0 or 16
    const f16* aptr = A + (size_t)(bm + srow) * K + skh;
    const f16* bptr = Bm + (size_t)(bn + srow) * K + skh;

    for (int k0 = 0; k0 < K; k0 += KT) {
        half8 a0 = *(const half8*)(aptr + k0);
        half8 a1 = *(const half8*)(aptr + k0 + 8);
        half8 b0 = *(const half8*)(bptr + k0);
        half8 b1 = *(const half8*)(bptr + k0 + 8);
        __syncthreads();
        *(half8*)&As[srow * KP + skh]     = a0;
        *(half8*)&As[srow * KP + skh + 8] = a1;
        *(half8*)&Bs[srow * KP + skh]     = b0;
        *(half8*)&Bs[srow * KP + skh + 8] = b1;
        __syncthreads();

        half8 af[4], bf[4];
#pragma unroll
        for (int i = 0; i < 4; ++i)
            af[i] = *(const half8*)&As[(wm + 16 * i + r16) * KP + kg * 8];
#pragma unroll
        for (int j = 0; j < 4; ++j)
            bf[j] = *(const half8*)&Bs[(wn + 16 * j + r16) * KP + kg * 8];
#pragma unroll
        for (int i = 0; i < 4; ++i)
#pragma unroll
            for (int j = 0; j < 4; ++j)
                acc[i][j] = __builtin_amdgcn_mfma_f32_16x16x32_f16(af[i], bf[j], acc[i][j], 0, 0, 0);
    }

    if (Ch) {
#pragma unroll
        for (int j = 0; j < 4; ++j) {
            const int col = bn + wn + 16 * j + r16;
            const float bv = bias[col];
#pragma unroll
            for (int i = 0; i < 4; ++i) {
                const int row0 = bm + wm + 16 * i + kg * 4;
#pragma unroll
                for (int r = 0; r < 4; ++r)
                    Ch[(size_t)(row0 + r) * N + col] = (f16)(acc[i][j][r] + bv);
            }
        }
    } else {
#pragma unroll
        for (int j = 0; j < 4; ++j) {
            const int col = bn + wn + 16 * j + r16;
            const float bv = bias[col];
#pragma unroll
            for (int i = 0; i < 4; ++i) {
                const int row0 = bm + wm + 16 * i + kg * 4;
#pragma unroll
                for (int r = 0; r < 4; ++r)
                    Cf[(size_t)(row0 + r) * N + col] = acc[i][j][r] + bv;
            }
        }
    }
}

// ---------------------------------------------------------------------------
// Attention v5 (MFMA, fp16 qkv in / fp16 ctx out). Structure = passing v4:
// 2 sweeps, no-max softmax, WS round-trip for PV operand layout.
// Staging is now pure fp16 copies (Q scaled by exact 0.125 in f16).
// ---------------------------------------------------------------------------
constexpr int AQT = 128;
constexpr int AKT = 128;
constexpr int AKP = 72;      // f16 stride [row][d]
constexpr int AWP = 136;     // f16 stride WS [q][k]
constexpr int AVP = 136;     // f16 stride Vt [d][k]

constexpr int AQ_OFF  = 0;                   // Kq 128*72 f16 = 4608 w
constexpr int AKV_OFF = 4608;                // Kt 4608 w | Vt 64*136 f16 = 4352 w
constexpr int AW_OFF  = AKV_OFF + 4608;      // WS 128*136 f16 = 8704 w
constexpr int ARS_OFF = AW_OFF + 8704;       // RS fp32 [128]
constexpr int ACOL_OFF = ARS_OFF + 128;      // COL fp32 [1024]
constexpr int ASMEM   = ACOL_OFF + 1024;     // 19072 w = 76288 B

__global__ __launch_bounds__(256, 2)
void attn_kernel(const f16* __restrict__ qkv, f16* __restrict__ ctx,
                 float* __restrict__ avg_out) {
    __shared__ __align__(16) float smemf[ASMEM];
    f16* Kq = (f16*)(smemf + AQ_OFF);    // [q][d] (scaled by 0.125)
    f16* Kt = (f16*)(smemf + AKV_OFF);   // [k][d]
    f16* Vt = (f16*)(smemf + AKV_OFF);   // [d][k] (union)
    f16* WS = (f16*)(smemf + AW_OFF);    // [q][k]
    float* RS  = smemf + ARS_OFF;
    float* COL = smemf + ACOL_OFF;

    const int tid = threadIdx.x;
    const int qt = blockIdx.x, h = blockIdx.y, b = blockIdx.z;
    const int l0 = qt * AQT;
    const size_t rowstride = 3 * Ec;     // f16 units
    const f16* base = qkv + (size_t)b * Lc * rowstride + (size_t)h * Dc;

    const int wave = tid >> 6, lane = tid & 63;
    const int r16 = lane & 15, kg = lane >> 4;
    const int wm = (wave >> 1) * 64;
    const int wn = (wave & 1) * 64;

    if (tid < 128) RS[tid] = 0.f;
#pragma unroll
    for (int t = 0; t < 4; ++t) COL[t * 256 + tid] = 0.f;

    const int srow = tid >> 1;
    const int sh = (tid & 1) * 32;       // f16 offset 0 or 32

    // stage Q (x 0.125, exact in f16)
    {
        const f16* src = base + (size_t)(l0 + srow) * rowstride + sh;
        f16* dst = Kq + srow * AKP + sh;
#pragma unroll
        for (int jj = 0; jj < 4; ++jj) {
            half8 p = *(const half8*)(src + jj * 8);
#pragma unroll
            for (int e = 0; e < 8; ++e) p[e] = p[e] * (f16)0.125f;
            *(half8*)(dst + jj * 8) = p;
        }
    }

    // ================= sweep 1: row sums of exp(scores) =================
    float rs[4][4];
#pragma unroll
    for (int i = 0; i < 4; ++i)
#pragma unroll
        for (int r = 0; r < 4; ++r) rs[i][r] = 0.f;

    for (int kt = 0; kt < Lc / AKT; ++kt) {
        __syncthreads();
        {
            const f16* src = base + (size_t)(kt * AKT + srow) * rowstride + Ec + sh;
            f16* dst = Kt + srow * AKP + sh;
#pragma unroll
            for (int jj = 0; jj < 4; ++jj)
                *(half8*)(dst + jj * 8) = *(const half8*)(src + jj * 8);
        }
        __syncthreads();

        floatx4 s[4][4];
#pragma unroll
        for (int i = 0; i < 4; ++i)
#pragma unroll
            for (int j = 0; j < 4; ++j) s[i][j] = (floatx4){0.f, 0.f, 0.f, 0.f};
#pragma unroll
        for (int ks = 0; ks < 2; ++ks) {
            half8 af[4], bf[4];
#pragma unroll
            for (int i = 0; i < 4; ++i)
                af[i] = *(const half8*)&Kq[(wm + 16 * i + r16) * AKP + ks * 32 + kg * 8];
#pragma unroll
            for (int j = 0; j < 4; ++j)
                bf[j] = *(const half8*)&Kt[(wn + 16 * j + r16) * AKP + ks * 32 + kg * 8];
#pragma unroll
            for (int i = 0; i < 4; ++i)
#pragma unroll
                for (int j = 0; j < 4; ++j)
                    s[i][j] = __builtin_amdgcn_mfma_f32_16x16x32_f16(af[i], bf[j], s[i][j], 0, 0, 0);
        }
#pragma unroll
        for (int i = 0; i < 4; ++i)
#pragma unroll
            for (int r = 0; r < 4; ++r)
                rs[i][r] += __expf(s[i][0][r]) + __expf(s[i][1][r]) +
                            __expf(s[i][2][r]) + __expf(s[i][3][r]);
    }

#pragma unroll
    for (int i = 0; i < 4; ++i)
#pragma unroll
        for (int r = 0; r < 4; ++r) {
            float v = rs[i][r];
            v += __shfl_xor(v, 1); v += __shfl_xor(v, 2);
            v += __shfl_xor(v, 4); v += __shfl_xor(v, 8);
            rs[i][r] = v;
        }
    if (r16 == 0) {
#pragma unroll
        for (int i = 0; i < 4; ++i)
#pragma unroll
            for (int r = 0; r < 4; ++r)
                atomicAdd(&RS[wm + 16 * i + 4 * kg + r], rs[i][r]);
    }
    __syncthreads();
    if (tid < 128) RS[tid] = 1.0f / RS[tid];
    __syncthreads();

    float rinv[4][4];
#pragma unroll
    for (int i = 0; i < 4; ++i)
#pragma unroll
        for (int r = 0; r < 4; ++r) rinv[i][r] = RS[wm + 16 * i + 4 * kg + r];

    // ================= sweep 2: w -> WS, col sums, PV =================
    floatx4 cacc[2][4];
#pragma unroll
    for (int p = 0; p < 2; ++p)
#pragma unroll
        for (int j = 0; j < 4; ++j) cacc[p][j] = (floatx4){0.f, 0.f, 0.f, 0.f};
    const int qb = wave * 32;

    for (int kt = 0; kt < Lc / AKT; ++kt) {
        __syncthreads();
        {
            const f16* src = base + (size_t)(kt * AKT + srow) * rowstride + Ec + sh;
            f16* dst = Kt + srow * AKP + sh;
#pragma unroll
            for (int jj = 0; jj < 4; ++jj)
                *(half8*)(dst + jj * 8) = *(const half8*)(src + jj * 8);
        }
        __syncthreads();

        floatx4 s[4][4];
#pragma unroll
        for (int i = 0; i < 4; ++i)
#pragma unroll
            for (int j = 0; j < 4; ++j) s[i][j] = (floatx4){0.f, 0.f, 0.f, 0.f};
#pragma unroll
        for (int ks = 0; ks < 2; ++ks) {
            half8 af[4], bf[4];
#pragma unroll
            for (int i = 0; i < 4; ++i)
                af[i] = *(const half8*)&Kq[(wm + 16 * i + r16) * AKP + ks * 32 + kg * 8];
#pragma unroll
            for (int j = 0; j < 4; ++j)
                bf[j] = *(const half8*)&Kt[(wn + 16 * j + r16) * AKP + ks * 32 + kg * 8];
#pragma unroll
            for (int i = 0; i < 4; ++i)
#pragma unroll
                for (int j = 0; j < 4; ++j)
                    s[i][j] = __builtin_amdgcn_mfma_f32_16x16x32_f16(af[i], bf[j], s[i][j], 0, 0, 0);
        }

        float cs[4] = {0.f, 0.f, 0.f, 0.f};
#pragma unroll
        for (int i = 0; i < 4; ++i)
#pragma unroll
            for (int j = 0; j < 4; ++j)
#pragma unroll
                for (int r = 0; r < 4; ++r) {
                    float w = __expf(s[i][j][r]) * rinv[i][r];
                    s[i][j][r] = w;
                    cs[j] += w;
                }

        __syncthreads();   // all Kt reads done -> Vt may overwrite

        // write w to WS[q][k]
#pragma unroll
        for (int i = 0; i < 4; ++i)
#pragma unroll
            for (int r = 0; r < 4; ++r) {
                f16* wrow = WS + (wm + 16 * i + 4 * kg + r) * AWP + wn + r16;
#pragma unroll
                for (int j = 0; j < 4; ++j) wrow[16 * j] = (f16)s[i][j][r];
            }

        // stage V^T: Vt[d][k] (fp16 copy-transpose)
        {
            const f16* src = base + (size_t)(kt * AKT + srow) * rowstride + 2 * Ec + sh;
#pragma unroll
            for (int jj = 0; jj < 4; ++jj) {
                half8 v = *(const half8*)(src + jj * 8);
#pragma unroll
                for (int e = 0; e < 8; ++e)
                    Vt[(sh + jj * 8 + e) * AVP + srow] = v[e];
            }
        }

        // col sums -> COL
#pragma unroll
        for (int j = 0; j < 4; ++j) {
            float c = cs[j];
            c += __shfl_xor(c, 16);
            c += __shfl_xor(c, 32);
            if (kg == 0) atomicAdd(&COL[kt * AKT + wn + 16 * j + r16], c);
        }

        __syncthreads();   // WS & Vt ready

        // PV
#pragma unroll
        for (int ks2 = 0; ks2 < 4; ++ks2) {
            half8 wa[2], vb[4];
#pragma unroll
            for (int p = 0; p < 2; ++p)
                wa[p] = *(const half8*)&WS[(qb + 16 * p + r16) * AWP + ks2 * 32 + kg * 8];
#pragma unroll
            for (int j = 0; j < 4; ++j)
                vb[j] = *(const half8*)&Vt[(16 * j + r16) * AVP + ks2 * 32 + kg * 8];
#pragma unroll
            for (int p = 0; p < 2; ++p)
#pragma unroll
                for (int j = 0; j < 4; ++j)
                    cacc[p][j] = __builtin_amdgcn_mfma_f32_16x16x32_f16(wa[p], vb[j], cacc[p][j], 0, 0, 0);
        }
    }

    // ---- epilogue: ctx (fp16) from accumulator fragments ----
#pragma unroll
    for (int p = 0; p < 2; ++p)
#pragma unroll
        for (int r = 0; r < 4; ++r) {
            f16* dst = ctx + (size_t)(b * Lc + l0 + qb + 16 * p + 4 * kg + r) * Ec + h * Dc + r16;
#pragma unroll
            for (int j = 0; j < 4; ++j) dst[16 * j] = (f16)cacc[p][j][r];
        }

    // ---- flush avg_attn ----
    __syncthreads();
#pragma unroll
    for (int t = 0; t < 4; ++t) {
        int m = t * 256 + tid;
        atomicAdd(&avg_out[b * Lc + m], COL[m] * (1.0f / (Hc * Lc)));
    }
}

// ---------------------------------------------------------------------------
// LayerNorm stats: one block per (b,l) row. h = x + attn_out.  (UNCHANGED)
// ---------------------------------------------------------------------------
__global__ __launch_bounds__(256)
void stats_kernel(const float* __restrict__ x, const float* __restrict__ attn_out,
                  float2* __restrict__ stats) {
    const int row = blockIdx.x;
    const int tid = threadIdx.x;
    const float* xp = x + (size_t)row * Ec;
    const float* ap = attn_out + (size_t)row * Ec;
    float4 xv = *(const float4*)(xp + tid * 4);
    float4 av = *(const float4*)(ap + tid * 4);
    float h0 = xv.x + av.x, h1 = xv.y + av.y, h2 = xv.z + av.z, h3 = xv.w + av.w;
    float s = h0 + h1 + h2 + h3;
    float ss = h0 * h0 + h1 * h1 + h2 * h2 + h3 * h3;
#pragma unroll
    for (int off = 32; off; off >>= 1) {
        s += __shfl_xor(s, off);
        ss += __shfl_xor(ss, off);
    }
    __shared__ float wsum[4], wsq[4];
    const int wave = tid >> 6, lane = tid & 63;
    if (lane == 0) { wsum[wave] = s; wsq[wave] = ss; }
    __syncthreads();
    if (tid == 0) {
        float ts = wsum[0] + wsum[1] + wsum[2] + wsum[3];
        float tq = wsq[0] + wsq[1] + wsq[2] + wsq[3];
        float mean = ts * (1.0f / Ec);
        float var = tq * (1.0f / Ec) - mean * mean;
        stats[row] = make_float2(mean, rsqrtf(var + EPSc));
    }
}

// ---------------------------------------------------------------------------
// Pooled output  (UNCHANGED)
// ---------------------------------------------------------------------------
__global__ __launch_bounds__(256)
void pool_kernel(const float* __restrict__ x, const float* __restrict__ attn_out,
                 const float2* __restrict__ stats, const float* __restrict__ gamma,
                 const float* __restrict__ beta, float* __restrict__ pooled) {
    const int b = blockIdx.z;
    const int f = blockIdx.y * 256 + threadIdx.x;
    const int l0 = blockIdx.x * 64;
    const float g = gamma[f];
    const float be = beta[f];
    float acc = 0.f;
    for (int l = l0; l < l0 + 64; ++l) {
        size_t idx = (size_t)(b * Lc + l) * Ec + f;
        float2 st = stats[b * Lc + l];
        float h = x[idx] + attn_out[idx];
        acc += (h - st.x) * st.y * g + be;
    }
    atomicAdd(&pooled[b * Ec + f], acc * (1.0f / Lc));
}

// ---------------------------------------------------------------------------
extern "C" void kernel_launch(void* const* d_in, const int* in_sizes, int n_in,
                              void* d_out, int out_size, void* d_ws, size_t ws_size,
                              hipStream_t stream) {
    const float* x      = (const float*)d_in[0];   // (B,L,E)
    const float* w_qkv  = (const float*)d_in[1];   // (3E,E)
    const float* b_qkv  = (const float*)d_in[2];   // (3E,)
    const float* w_out  = (const float*)d_in[3];   // (E,E)
    const float* b_out  = (const float*)d_in[4];   // (E,)
    const float* gamma  = (const float*)d_in[5];   // (E,)
    const float* beta   = (const float*)d_in[6];   // (E,)
    float* out = (float*)d_out;                    // pooled (B,E) then avg_attn (B,L)

    // workspace layout (f16 units first, then f32):
    //  qkv_h   25165824 f16
    //  ctx_h    8388608 f16
    //  x_h      8388608 f16
    //  wqkv_h   3145728 f16
    //  wout_h   1048576 f16   (total 46137344 f16 = 92274688 B)
    //  attn_out 8388608 f32
    //  stats      16384 f32   (total ~120.1 MB; previous layout used 134 MB)
    f16* wsh = (f16*)d_ws;
    f16* qkv_h  = wsh;
    f16* ctx_h  = qkv_h + (size_t)25165824;
    f16* x_h    = ctx_h + (size_t)8388608;
    f16* wqkv_h = x_h + (size_t)8388608;
    f16* wout_h = wqkv_h + (size_t)3145728;
    float* attn_out = (float*)(wout_h + (size_t)1048576);
    float* stats = attn_out + (size_t)8388608;

    const int M = Bc * Lc;   // 8192

    hipMemsetAsync(d_out, 0, (size_t)out_size * sizeof(float), stream);

    // 0) one-time fp32 -> fp16 conversions
    cvt_f32_f16_kernel<<<2048, 256, 0, stream>>>(x, x_h, (Bc * Lc * Ec) / 8);
    cvt_f32_f16_kernel<<<1536, 256, 0, stream>>>(w_qkv, wqkv_h, (3 * Ec * Ec) / 8);
    cvt_f32_f16_kernel<<<512, 256, 0, stream>>>(w_out, wout_h, (Ec * Ec) / 8);

    // 1) QKV projection -> fp16 qkv
    dim3 g1(M / 128, (3 * Ec) / 128);
    gemm_nt_h<<<g1, 256, 0, stream>>>(x_h, wqkv_h, b_qkv, nullptr, qkv_h, M, 3 * Ec, Ec);

    // 2) attention + avg_attn -> fp16 ctx
    dim3 g2(Lc / AQT, Hc, Bc);
    attn_kernel<<<g2, 256, 0, stream>>>(qkv_h, ctx_h, out + Bc * Ec);

    // 3) output projection -> fp32 attn_out
    dim3 g3(M / 128, Ec / 128);
    gemm_nt_h<<<g3, 256, 0, stream>>>(ctx_h, wout_h, b_out, attn_out, nullptr, M, Ec, Ec);

    // 4) LN stats
    stats_kernel<<<M, 256, 0, stream>>>(x, attn_out, (float2*)stats);

    // 5) pooled
    dim3 g5(16, 4, Bc);
    pool_kernel<<<g5, 256, 0, stream>>>(x, attn_out, (float2*)stats, gamma, beta, out);
}

// Round 7
// 342.104 us; speedup vs baseline: 10.3521x; 1.0392x over previous
//
#include <hip/hip_runtime.h>
#include <math.h>

// Problem constants (B,L,E,H,D) = (8,1024,1024,16,64)
constexpr int Bc = 8;
constexpr int Lc = 1024;
constexpr int Ec = 1024;
constexpr int Hc = 16;
constexpr int Dc = 64;
constexpr float EPSc = 1e-5f;

// ---- fp16 types ----
typedef _Float16 f16;
typedef f16 half8 __attribute__((ext_vector_type(8)));
typedef float floatx4 __attribute__((ext_vector_type(4)));

// async global->LDS 16B (direct-to-shared DMA; dest = wave-uniform base + lane*16)
static __device__ inline void gload_lds16(const f16* g, f16* l) {
    __builtin_amdgcn_global_load_lds(
        (const __attribute__((address_space(1))) void*)g,
        (__attribute__((address_space(3))) void*)l, 16, 0, 0);
}

// ---------------------------------------------------------------------------
// fp32 -> fp16 conversion (one-time). n8 = elems/8.  (UNCHANGED)
// ---------------------------------------------------------------------------
__global__ __launch_bounds__(256)
void cvt_f32_f16_kernel(const float* __restrict__ src, f16* __restrict__ dst, int n8) {
    int i = blockIdx.x * 256 + threadIdx.x;
    const int stride = gridDim.x * 256;
    for (; i < n8; i += stride) {
        float4 a = *(const float4*)(src + (size_t)i * 8);
        float4 b = *(const float4*)(src + (size_t)i * 8 + 4);
        half8 p;
        p[0] = (f16)a.x; p[1] = (f16)a.y; p[2] = (f16)a.z; p[3] = (f16)a.w;
        p[4] = (f16)b.x; p[5] = (f16)b.y; p[6] = (f16)b.z; p[7] = (f16)b.w;
        *(half8*)(dst + (size_t)i * 8) = p;
    }
}

// ---------------------------------------------------------------------------
// GEMM v3 (MFMA fp16 + global_load_lds staging): C = A*B^T + bias.
// A[M][K], B[N][K] fp16 K-contiguous. 128x128 tile, 4 waves 2x2 (64x64 each,
// 4x4 MFMA 16x16x32), KT=32. LDS: linear [128][32] f16 (64B rows), chunk-XOR
// swizzled: 16B chunk at (row, x) holds global k-chunk x^((row>>1)&3).
// Source pre-swizzled, read applies same XOR (rule #21: both-sides).
// Bank audit (b128 frag read): bucket=(row&1, kg^((r16>>1)&3)) -> 8 buckets x
// 4 banks, 8 lanes/bucket = b128 floor, no excess conflict.
// ---------------------------------------------------------------------------
__global__ __launch_bounds__(256)
void gemm_nt_h(const f16* __restrict__ A, const f16* __restrict__ Bm,
               const float* __restrict__ bias, float* __restrict__ Cf,
               f16* __restrict__ Ch, int M, int N, int K) {
    constexpr int TILE = 128;
    constexpr int KT = 32;
    __shared__ __align__(16) f16 As[TILE * KT];   // 8 KB
    __shared__ __align__(16) f16 Bs[TILE * KT];   // 8 KB

    const int tid = threadIdx.x;
    const int bm = blockIdx.x * TILE;
    const int bn = blockIdx.y * TILE;

    const int wave = tid >> 6;
    const int lane = tid & 63;
    const int wm = (wave >> 1) * 64;
    const int wn = (wave & 1) * 64;
    const int r16 = lane & 15;
    const int kg = lane >> 4;
    const int kswz = kg ^ ((r16 >> 1) & 3);   // read-side XOR (wm/wn,16i are 0 mod 4 after >>1... verified)

    floatx4 acc[4][4];
#pragma unroll
    for (int i = 0; i < 4; ++i)
#pragma unroll
        for (int j = 0; j < 4; ++j) acc[i][j] = (floatx4){0.f, 0.f, 0.f, 0.f};

    // staging: 512 16B-chunks per matrix per K-step; thread t handles chunks
    // c0 = t (rows 0..63) and c1 = 256+t (rows 64..127).
    const int c0 = tid, c1 = 256 + tid;
    const int row0 = c0 >> 2, row1 = c1 >> 2;
    const int kc0 = (c0 & 3) ^ ((row0 >> 1) & 3);   // pre-swizzled global k-chunk
    const int kc1 = (c1 & 3) ^ ((row1 >> 1) & 3);
    const f16* a0p = A + (size_t)(bm + row0) * K + kc0 * 8;
    const f16* a1p = A + (size_t)(bm + row1) * K + kc1 * 8;
    const f16* b0p = Bm + (size_t)(bn + row0) * K + kc0 * 8;
    const f16* b1p = Bm + (size_t)(bn + row1) * K + kc1 * 8;
    f16* asl0 = As + c0 * 8;   // chunk c -> LDS offset c*16B (linear)
    f16* asl1 = As + c1 * 8;
    f16* bsl0 = Bs + c0 * 8;
    f16* bsl1 = Bs + c1 * 8;

    for (int k0 = 0; k0 < K; k0 += KT) {
        __syncthreads();              // prior iteration's ds_reads complete
        gload_lds16(a0p + k0, asl0);
        gload_lds16(a1p + k0, asl1);
        gload_lds16(b0p + k0, bsl0);
        gload_lds16(b1p + k0, bsl1);
        __syncthreads();              // compiler drains vmcnt(0) before barrier

        half8 af[4], bf[4];
#pragma unroll
        for (int i = 0; i < 4; ++i)
            af[i] = *(const half8*)&As[(wm + 16 * i + r16) * KT + kswz * 8];
#pragma unroll
        for (int j = 0; j < 4; ++j)
            bf[j] = *(const half8*)&Bs[(wn + 16 * j + r16) * KT + kswz * 8];
#pragma unroll
        for (int i = 0; i < 4; ++i)
#pragma unroll
            for (int j = 0; j < 4; ++j)
                acc[i][j] = __builtin_amdgcn_mfma_f32_16x16x32_f16(af[i], bf[j], acc[i][j], 0, 0, 0);
    }

    if (Ch) {
#pragma unroll
        for (int j = 0; j < 4; ++j) {
            const int col = bn + wn + 16 * j + r16;
            const float bv = bias[col];
#pragma unroll
            for (int i = 0; i < 4; ++i) {
                const int row0e = bm + wm + 16 * i + kg * 4;
#pragma unroll
                for (int r = 0; r < 4; ++r)
                    Ch[(size_t)(row0e + r) * N + col] = (f16)(acc[i][j][r] + bv);
            }
        }
    } else {
#pragma unroll
        for (int j = 0; j < 4; ++j) {
            const int col = bn + wn + 16 * j + r16;
            const float bv = bias[col];
#pragma unroll
            for (int i = 0; i < 4; ++i) {
                const int row0e = bm + wm + 16 * i + kg * 4;
#pragma unroll
                for (int r = 0; r < 4; ++r)
                    Cf[(size_t)(row0e + r) * N + col] = acc[i][j][r] + bv;
            }
        }
    }
}

// ---------------------------------------------------------------------------
// Attention v5 (UNCHANGED from passing round 6): MFMA, fp16 qkv in / fp16 ctx out.
// ---------------------------------------------------------------------------
constexpr int AQT = 128;
constexpr int AKT = 128;
constexpr int AKP = 72;      // f16 stride [row][d]
constexpr int AWP = 136;     // f16 stride WS [q][k]
constexpr int AVP = 136;     // f16 stride Vt [d][k]

constexpr int AQ_OFF  = 0;                   // Kq 128*72 f16 = 4608 w
constexpr int AKV_OFF = 4608;                // Kt 4608 w | Vt 64*136 f16 = 4352 w
constexpr int AW_OFF  = AKV_OFF + 4608;      // WS 128*136 f16 = 8704 w
constexpr int ARS_OFF = AW_OFF + 8704;       // RS fp32 [128]
constexpr int ACOL_OFF = ARS_OFF + 128;      // COL fp32 [1024]
constexpr int ASMEM   = ACOL_OFF + 1024;     // 19072 w = 76288 B

__global__ __launch_bounds__(256, 2)
void attn_kernel(const f16* __restrict__ qkv, f16* __restrict__ ctx,
                 float* __restrict__ avg_out) {
    __shared__ __align__(16) float smemf[ASMEM];
    f16* Kq = (f16*)(smemf + AQ_OFF);    // [q][d] (scaled by 0.125)
    f16* Kt = (f16*)(smemf + AKV_OFF);   // [k][d]
    f16* Vt = (f16*)(smemf + AKV_OFF);   // [d][k] (union)
    f16* WS = (f16*)(smemf + AW_OFF);    // [q][k]
    float* RS  = smemf + ARS_OFF;
    float* COL = smemf + ACOL_OFF;

    const int tid = threadIdx.x;
    const int qt = blockIdx.x, h = blockIdx.y, b = blockIdx.z;
    const int l0 = qt * AQT;
    const size_t rowstride = 3 * Ec;     // f16 units
    const f16* base = qkv + (size_t)b * Lc * rowstride + (size_t)h * Dc;

    const int wave = tid >> 6, lane = tid & 63;
    const int r16 = lane & 15, kg = lane >> 4;
    const int wm = (wave >> 1) * 64;
    const int wn = (wave & 1) * 64;

    if (tid < 128) RS[tid] = 0.f;
#pragma unroll
    for (int t = 0; t < 4; ++t) COL[t * 256 + tid] = 0.f;

    const int srow = tid >> 1;
    const int sh = (tid & 1) * 32;       // f16 offset 0 or 32

    // stage Q (x 0.125, exact in f16)
    {
        const f16* src = base + (size_t)(l0 + srow) * rowstride + sh;
        f16* dst = Kq + srow * AKP + sh;
#pragma unroll
        for (int jj = 0; jj < 4; ++jj) {
            half8 p = *(const half8*)(src + jj * 8);
#pragma unroll
            for (int e = 0; e < 8; ++e) p[e] = p[e] * (f16)0.125f;
            *(half8*)(dst + jj * 8) = p;
        }
    }

    // ================= sweep 1: row sums of exp(scores) =================
    float rs[4][4];
#pragma unroll
    for (int i = 0; i < 4; ++i)
#pragma unroll
        for (int r = 0; r < 4; ++r) rs[i][r] = 0.f;

    for (int kt = 0; kt < Lc / AKT; ++kt) {
        __syncthreads();
        {
            const f16* src = base + (size_t)(kt * AKT + srow) * rowstride + Ec + sh;
            f16* dst = Kt + srow * AKP + sh;
#pragma unroll
            for (int jj = 0; jj < 4; ++jj)
                *(half8*)(dst + jj * 8) = *(const half8*)(src + jj * 8);
        }
        __syncthreads();

        floatx4 s[4][4];
#pragma unroll
        for (int i = 0; i < 4; ++i)
#pragma unroll
            for (int j = 0; j < 4; ++j) s[i][j] = (floatx4){0.f, 0.f, 0.f, 0.f};
#pragma unroll
        for (int ks = 0; ks < 2; ++ks) {
            half8 af[4], bf[4];
#pragma unroll
            for (int i = 0; i < 4; ++i)
                af[i] = *(const half8*)&Kq[(wm + 16 * i + r16) * AKP + ks * 32 + kg * 8];
#pragma unroll
            for (int j = 0; j < 4; ++j)
                bf[j] = *(const half8*)&Kt[(wn + 16 * j + r16) * AKP + ks * 32 + kg * 8];
#pragma unroll
            for (int i = 0; i < 4; ++i)
#pragma unroll
                for (int j = 0; j < 4; ++j)
                    s[i][j] = __builtin_amdgcn_mfma_f32_16x16x32_f16(af[i], bf[j], s[i][j], 0, 0, 0);
        }
#pragma unroll
        for (int i = 0; i < 4; ++i)
#pragma unroll
            for (int r = 0; r < 4; ++r)
                rs[i][r] += __expf(s[i][0][r]) + __expf(s[i][1][r]) +
                            __expf(s[i][2][r]) + __expf(s[i][3][r]);
    }

#pragma unroll
    for (int i = 0; i < 4; ++i)
#pragma unroll
        for (int r = 0; r < 4; ++r) {
            float v = rs[i][r];
            v += __shfl_xor(v, 1); v += __shfl_xor(v, 2);
            v += __shfl_xor(v, 4); v += __shfl_xor(v, 8);
            rs[i][r] = v;
        }
    if (r16 == 0) {
#pragma unroll
        for (int i = 0; i < 4; ++i)
#pragma unroll
            for (int r = 0; r < 4; ++r)
                atomicAdd(&RS[wm + 16 * i + 4 * kg + r], rs[i][r]);
    }
    __syncthreads();
    if (tid < 128) RS[tid] = 1.0f / RS[tid];
    __syncthreads();

    float rinv[4][4];
#pragma unroll
    for (int i = 0; i < 4; ++i)
#pragma unroll
        for (int r = 0; r < 4; ++r) rinv[i][r] = RS[wm + 16 * i + 4 * kg + r];

    // ================= sweep 2: w -> WS, col sums, PV =================
    floatx4 cacc[2][4];
#pragma unroll
    for (int p = 0; p < 2; ++p)
#pragma unroll
        for (int j = 0; j < 4; ++j) cacc[p][j] = (floatx4){0.f, 0.f, 0.f, 0.f};
    const int qb = wave * 32;

    for (int kt = 0; kt < Lc / AKT; ++kt) {
        __syncthreads();
        {
            const f16* src = base + (size_t)(kt * AKT + srow) * rowstride + Ec + sh;
            f16* dst = Kt + srow * AKP + sh;
#pragma unroll
            for (int jj = 0; jj < 4; ++jj)
                *(half8*)(dst + jj * 8) = *(const half8*)(src + jj * 8);
        }
        __syncthreads();

        floatx4 s[4][4];
#pragma unroll
        for (int i = 0; i < 4; ++i)
#pragma unroll
            for (int j = 0; j < 4; ++j) s[i][j] = (floatx4){0.f, 0.f, 0.f, 0.f};
#pragma unroll
        for (int ks = 0; ks < 2; ++ks) {
            half8 af[4], bf[4];
#pragma unroll
            for (int i = 0; i < 4; ++i)
                af[i] = *(const half8*)&Kq[(wm + 16 * i + r16) * AKP + ks * 32 + kg * 8];
#pragma unroll
            for (int j = 0; j < 4; ++j)
                bf[j] = *(const half8*)&Kt[(wn + 16 * j + r16) * AKP + ks * 32 + kg * 8];
#pragma unroll
            for (int i = 0; i < 4; ++i)
#pragma unroll
                for (int j = 0; j < 4; ++j)
                    s[i][j] = __builtin_amdgcn_mfma_f32_16x16x32_f16(af[i], bf[j], s[i][j], 0, 0, 0);
        }

        float cs[4] = {0.f, 0.f, 0.f, 0.f};
#pragma unroll
        for (int i = 0; i < 4; ++i)
#pragma unroll
            for (int j = 0; j < 4; ++j)
#pragma unroll
                for (int r = 0; r < 4; ++r) {
                    float w = __expf(s[i][j][r]) * rinv[i][r];
                    s[i][j][r] = w;
                    cs[j] += w;
                }

        __syncthreads();   // all Kt reads done -> Vt may overwrite

        // write w to WS[q][k]
#pragma unroll
        for (int i = 0; i < 4; ++i)
#pragma unroll
            for (int r = 0; r < 4; ++r) {
                f16* wrow = WS + (wm + 16 * i + 4 * kg + r) * AWP + wn + r16;
#pragma unroll
                for (int j = 0; j < 4; ++j) wrow[16 * j] = (f16)s[i][j][r];
            }

        // stage V^T: Vt[d][k] (fp16 copy-transpose)
        {
            const f16* src = base + (size_t)(kt * AKT + srow) * rowstride + 2 * Ec + sh;
#pragma unroll
            for (int jj = 0; jj < 4; ++jj) {
                half8 v = *(const half8*)(src + jj * 8);
#pragma unroll
                for (int e = 0; e < 8; ++e)
                    Vt[(sh + jj * 8 + e) * AVP + srow] = v[e];
            }
        }

        // col sums -> COL
#pragma unroll
        for (int j = 0; j < 4; ++j) {
            float c = cs[j];
            c += __shfl_xor(c, 16);
            c += __shfl_xor(c, 32);
            if (kg == 0) atomicAdd(&COL[kt * AKT + wn + 16 * j + r16], c);
        }

        __syncthreads();   // WS & Vt ready

        // PV
#pragma unroll
        for (int ks2 = 0; ks2 < 4; ++ks2) {
            half8 wa[2], vb[4];
#pragma unroll
            for (int p = 0; p < 2; ++p)
                wa[p] = *(const half8*)&WS[(qb + 16 * p + r16) * AWP + ks2 * 32 + kg * 8];
#pragma unroll
            for (int j = 0; j < 4; ++j)
                vb[j] = *(const half8*)&Vt[(16 * j + r16) * AVP + ks2 * 32 + kg * 8];
#pragma unroll
            for (int p = 0; p < 2; ++p)
#pragma unroll
                for (int j = 0; j < 4; ++j)
                    cacc[p][j] = __builtin_amdgcn_mfma_f32_16x16x32_f16(wa[p], vb[j], cacc[p][j], 0, 0, 0);
        }
    }

    // ---- epilogue: ctx (fp16) from accumulator fragments ----
#pragma unroll
    for (int p = 0; p < 2; ++p)
#pragma unroll
        for (int r = 0; r < 4; ++r) {
            f16* dst = ctx + (size_t)(b * Lc + l0 + qb + 16 * p + 4 * kg + r) * Ec + h * Dc + r16;
#pragma unroll
            for (int j = 0; j < 4; ++j) dst[16 * j] = (f16)cacc[p][j][r];
        }

    // ---- flush avg_attn ----
    __syncthreads();
#pragma unroll
    for (int t = 0; t < 4; ++t) {
        int m = t * 256 + tid;
        atomicAdd(&avg_out[b * Lc + m], COL[m] * (1.0f / (Hc * Lc)));
    }
}

// ---------------------------------------------------------------------------
// LayerNorm stats: one block per (b,l) row. h = x + attn_out.  (UNCHANGED)
// ---------------------------------------------------------------------------
__global__ __launch_bounds__(256)
void stats_kernel(const float* __restrict__ x, const float* __restrict__ attn_out,
                  float2* __restrict__ stats) {
    const int row = blockIdx.x;
    const int tid = threadIdx.x;
    const float* xp = x + (size_t)row * Ec;
    const float* ap = attn_out + (size_t)row * Ec;
    float4 xv = *(const float4*)(xp + tid * 4);
    float4 av = *(const float4*)(ap + tid * 4);
    float h0 = xv.x + av.x, h1 = xv.y + av.y, h2 = xv.z + av.z, h3 = xv.w + av.w;
    float s = h0 + h1 + h2 + h3;
    float ss = h0 * h0 + h1 * h1 + h2 * h2 + h3 * h3;
#pragma unroll
    for (int off = 32; off; off >>= 1) {
        s += __shfl_xor(s, off);
        ss += __shfl_xor(ss, off);
    }
    __shared__ float wsum[4], wsq[4];
    const int wave = tid >> 6, lane = tid & 63;
    if (lane == 0) { wsum[wave] = s; wsq[wave] = ss; }
    __syncthreads();
    if (tid == 0) {
        float ts = wsum[0] + wsum[1] + wsum[2] + wsum[3];
        float tq = wsq[0] + wsq[1] + wsq[2] + wsq[3];
        float mean = ts * (1.0f / Ec);
        float var = tq * (1.0f / Ec) - mean * mean;
        stats[row] = make_float2(mean, rsqrtf(var + EPSc));
    }
}

// ---------------------------------------------------------------------------
// Pooled output  (UNCHANGED)
// ---------------------------------------------------------------------------
__global__ __launch_bounds__(256)
void pool_kernel(const float* __restrict__ x, const float* __restrict__ attn_out,
                 const float2* __restrict__ stats, const float* __restrict__ gamma,
                 const float* __restrict__ beta, float* __restrict__ pooled) {
    const int b = blockIdx.z;
    const int f = blockIdx.y * 256 + threadIdx.x;
    const int l0 = blockIdx.x * 64;
    const float g = gamma[f];
    const float be = beta[f];
    float acc = 0.f;
    for (int l = l0; l < l0 + 64; ++l) {
        size_t idx = (size_t)(b * Lc + l) * Ec + f;
        float2 st = stats[b * Lc + l];
        float h = x[idx] + attn_out[idx];
        acc += (h - st.x) * st.y * g + be;
    }
    atomicAdd(&pooled[b * Ec + f], acc * (1.0f / Lc));
}

// ---------------------------------------------------------------------------
extern "C" void kernel_launch(void* const* d_in, const int* in_sizes, int n_in,
                              void* d_out, int out_size, void* d_ws, size_t ws_size,
                              hipStream_t stream) {
    const float* x      = (const float*)d_in[0];   // (B,L,E)
    const float* w_qkv  = (const float*)d_in[1];   // (3E,E)
    const float* b_qkv  = (const float*)d_in[2];   // (3E,)
    const float* w_out  = (const float*)d_in[3];   // (E,E)
    const float* b_out  = (const float*)d_in[4];   // (E,)
    const float* gamma  = (const float*)d_in[5];   // (E,)
    const float* beta   = (const float*)d_in[6];   // (E,)
    float* out = (float*)d_out;                    // pooled (B,E) then avg_attn (B,L)

    // workspace layout (f16 units first, then f32)
    f16* wsh = (f16*)d_ws;
    f16* qkv_h  = wsh;
    f16* ctx_h  = qkv_h + (size_t)25165824;
    f16* x_h    = ctx_h + (size_t)8388608;
    f16* wqkv_h = x_h + (size_t)8388608;
    f16* wout_h = wqkv_h + (size_t)3145728;
    float* attn_out = (float*)(wout_h + (size_t)1048576);
    float* stats = attn_out + (size_t)8388608;

    const int M = Bc * Lc;   // 8192

    hipMemsetAsync(d_out, 0, (size_t)out_size * sizeof(float), stream);

    // 0) one-time fp32 -> fp16 conversions
    cvt_f32_f16_kernel<<<2048, 256, 0, stream>>>(x, x_h, (Bc * Lc * Ec) / 8);
    cvt_f32_f16_kernel<<<1536, 256, 0, stream>>>(w_qkv, wqkv_h, (3 * Ec * Ec) / 8);
    cvt_f32_f16_kernel<<<512, 256, 0, stream>>>(w_out, wout_h, (Ec * Ec) / 8);

    // 1) QKV projection -> fp16 qkv
    dim3 g1(M / 128, (3 * Ec) / 128);
    gemm_nt_h<<<g1, 256, 0, stream>>>(x_h, wqkv_h, b_qkv, nullptr, qkv_h, M, 3 * Ec, Ec);

    // 2) attention + avg_attn -> fp16 ctx
    dim3 g2(Lc / AQT, Hc, Bc);
    attn_kernel<<<g2, 256, 0, stream>>>(qkv_h, ctx_h, out + Bc * Ec);

    // 3) output projection -> fp32 attn_out
    dim3 g3(M / 128, Ec / 128);
    gemm_nt_h<<<g3, 256, 0, stream>>>(ctx_h, wout_h, b_out, attn_out, nullptr, M, Ec, Ec);

    // 4) LN stats
    stats_kernel<<<M, 256, 0, stream>>>(x, attn_out, (float2*)stats);

    // 5) pooled
    dim3 g5(16, 4, Bc);
    pool_kernel<<<g5, 256, 0, stream>>>(x, attn_out, (float2*)stats, gamma, beta, out);
}